// Round 2
// baseline (2352.779 us; speedup 1.0000x reference)
//
#include <hip/hip_runtime.h>
#include <hip/hip_bf16.h>

#define NPTS 1000000
#define NVOX 200000
#define NCLS 20

typedef __hip_bfloat16 bf16;

// ---------- workspace layout (fp32 words) ----------
constexpr size_t L_PTS  = 0;                       // N*5 fp32 normalized points
constexpr size_t L_PV   = L_PTS + (size_t)NPTS*5;  // N int32 voxel ids
constexpr size_t L_BID  = L_PV + NPTS;             // N int32 batch ids
constexpr size_t L_VOX  = L_BID + NPTS;            // V*32 fp32 (zero-init)
constexpr size_t L_BSUM = L_VOX + (size_t)NVOX*32; // 256
constexpr size_t L_BCNT = L_BSUM + 256;            // 4
constexpr size_t L_GATE = L_BCNT + 4;              // 256
constexpr size_t L_FLAG = L_GATE + 256;            // 4 ints
constexpr size_t L_W    = L_FLAG + 4;              // folded weights
// weight offsets inside W
constexpr int O_PE1W = 0;      constexpr int O_PE1B = 128;
constexpr int O_PE2W = 160;    constexpr int O_PE2B = 2208;
constexpr int O_PE3W = 2272;   constexpr int O_PE3B = 4320;
constexpr int O_VE1W = 4352;   constexpr int O_VE1B = 5376;
constexpr int O_VE2W = 5408;   constexpr int O_VE2B = 6432;
constexpr int O_FUW  = 6464;   constexpr int O_FUB  = 10560;
constexpr int O_SE1W = 10624;  constexpr int O_SE1B = 10880;
constexpr int O_SE2W = 10884;  constexpr int O_SE2B = 11140;
constexpr int O_CLS1W = 11204; constexpr int O_CLS1B = 13252;
constexpr int O_CLS2W = 13284;
constexpr int O_AUX1W = 13924; constexpr int O_AUX1B = 14948;
constexpr int O_AUX2W = 14980;
constexpr int W_TOTAL = 15620;
constexpr size_t L_VFU = L_W + W_TOTAL;             // V*16 packed bf16 pairs (16B aligned)
constexpr size_t L_PFU = L_VFU + (size_t)NVOX*16;   // N*16 packed bf16 pairs
static_assert((L_VFU * 4) % 16 == 0, "vf alignment");

static __device__ __forceinline__ float b2f(bf16 v) { return __bfloat162float(v); }
static __device__ __forceinline__ unsigned short f2us(float f) {
    unsigned u = __float_as_uint(f);
    u += 0x7fffu + ((u >> 16) & 1u);
    return (unsigned short)(u >> 16);
}
static __device__ __forceinline__ unsigned pack2(float a, float b) {
    return (unsigned)f2us(a) | ((unsigned)f2us(b) << 16);
}
static __device__ __forceinline__ void unpack2(unsigned u, float& a, float& b) {
    a = __uint_as_float(u << 16);
    b = __uint_as_float(u & 0xffff0000u);
}
// dtype-agnostic float read (fp32 flag uniform)
static __device__ __forceinline__ float rdf(const void* p, size_t idx, int fp32) {
    return fp32 ? ((const float*)p)[idx] : b2f(((const bf16*)p)[idx]);
}

template <int K, int M, bool RELU, bool BIAS>
static __device__ __forceinline__ void dense(const float* __restrict__ x, float* __restrict__ y,
                                             const float* __restrict__ w, const float* __restrict__ b) {
#pragma unroll
    for (int j = 0; j < M; ++j) {
        float a = BIAS ? b[j] : 0.f;
#pragma unroll
        for (int k = 0; k < K; ++k) a = fmaf(x[k], w[k * M + j], a);
        y[j] = RELU ? fmaxf(a, 0.f) : a;
    }
}

// ---------- K0a: detect input dtypes from data ----------
__global__ void k0_detect(const unsigned short* __restrict__ ptsu,
                          const unsigned* __restrict__ pvu, int* __restrict__ flags) {
    if (threadIdx.x == 0) {
        // fp32 points: u16[1] is high half of batch_id 0.0f == 0; u16[11] high half of 0.0f too.
        // bf16 points: those are Gaussian coords -> nonzero.
        int fp32 = (ptsu[1] == 0 && ptsu[11] == 0) ? 1 : 0;
        // int64 ids: odd 32-bit words are high halves of values < 2^31 -> all 0.
        int i64 = (pvu[1] == 0 && pvu[3] == 0 && pvu[5] == 0 && pvu[7] == 0) ? 1 : 0;
        flags[0] = fp32;
        flags[1] = i64;
    }
}

// ---------- K0b: normalize points / ids to fp32 / int32 ----------
__global__ __launch_bounds__(256) void k0_norm(const void* __restrict__ pts_raw,
                                               const void* __restrict__ pv_raw,
                                               const int* __restrict__ flags,
                                               float* __restrict__ ptsN,
                                               int* __restrict__ pvN,
                                               int* __restrict__ bidN) {
    int fp32 = flags[0], i64 = flags[1];
    int i0 = blockIdx.x * 256 + threadIdx.x;
    int stride = gridDim.x * 256;
    for (size_t idx = i0; idx < (size_t)NPTS * 5; idx += stride)
        ptsN[idx] = rdf(pts_raw, idx, fp32);
    for (size_t idx = i0; idx < NPTS; idx += stride) {
        pvN[idx] = i64 ? (int)((const long long*)pv_raw)[idx] : ((const int*)pv_raw)[idx];
        bidN[idx] = (int)rdf(pts_raw, idx * 5, fp32);
    }
}

// ---------- K0c: fold BN into weights, fp32 master copy ----------
struct WPtrs {
    const void *pe_w1, *pe_g1, *pe_b1, *pe_w2, *pe_g2, *pe_b2, *pe_w3, *pe_g3, *pe_b3;
    const void *ve_w1, *ve_g1, *ve_b1, *ve_w2, *ve_g2, *ve_b2;
    const void *fu_w, *fu_g, *fu_b;
    const void *se_w1, *se_b1, *se_w2, *se_b2;
    const void *cls_w1, *cls_g1, *cls_b1, *cls_w2;
    const void *aux_w1, *aux_g1, *aux_b1, *aux_w2;
};

static __device__ void foldw(float* d, const void* w, const void* g, int K, int M, int fp32) {
    const float INV = 0.9999950000374997f;  // 1/sqrt(1+1e-5)
    for (int idx = threadIdx.x; idx < K * M; idx += 256)
        d[idx] = rdf(w, idx, fp32) * (rdf(g, idx % M, fp32) * INV);
}
static __device__ void cpv(float* d, const void* s, int n, int fp32) {
    for (int idx = threadIdx.x; idx < n; idx += 256) d[idx] = rdf(s, idx, fp32);
}

__global__ void k0_prep(WPtrs p, const int* __restrict__ flags, float* __restrict__ W) {
    int f32 = flags[0];
    foldw(W + O_PE1W, p.pe_w1, p.pe_g1, 4, 32, f32);   cpv(W + O_PE1B, p.pe_b1, 32, f32);
    foldw(W + O_PE2W, p.pe_w2, p.pe_g2, 32, 64, f32);  cpv(W + O_PE2B, p.pe_b2, 64, f32);
    foldw(W + O_PE3W, p.pe_w3, p.pe_g3, 64, 32, f32);  cpv(W + O_PE3B, p.pe_b3, 32, f32);
    foldw(W + O_VE1W, p.ve_w1, p.ve_g1, 32, 32, f32);  cpv(W + O_VE1B, p.ve_b1, 32, f32);
    foldw(W + O_VE2W, p.ve_w2, p.ve_g2, 32, 32, f32);  cpv(W + O_VE2B, p.ve_b2, 32, f32);
    foldw(W + O_FUW,  p.fu_w,  p.fu_g,  64, 64, f32);  cpv(W + O_FUB,  p.fu_b, 64, f32);
    cpv(W + O_SE1W, p.se_w1, 256, f32);  cpv(W + O_SE1B, p.se_b1, 4, f32);
    cpv(W + O_SE2W, p.se_w2, 256, f32);  cpv(W + O_SE2B, p.se_b2, 64, f32);
    foldw(W + O_CLS1W, p.cls_w1, p.cls_g1, 64, 32, f32); cpv(W + O_CLS1B, p.cls_b1, 32, f32);
    cpv(W + O_CLS2W, p.cls_w2, 640, f32);
    foldw(W + O_AUX1W, p.aux_w1, p.aux_g1, 32, 32, f32); cpv(W + O_AUX1B, p.aux_b1, 32, f32);
    cpv(W + O_AUX2W, p.aux_w2, 640, f32);
}

// ---------- K1: point MLP (4->32->64->32) + segment-max ----------
__global__ __launch_bounds__(256) void k1_point(const float* __restrict__ ptsN,
                                                const int* __restrict__ pv,
                                                const float* __restrict__ W,
                                                unsigned* __restrict__ pf_u,
                                                float* __restrict__ vox) {
    int i = blockIdx.x * 256 + threadIdx.x;
    bool valid = i < NPTS;
    int ic = valid ? i : NPTS - 1;
    float x[4];
#pragma unroll
    for (int k = 0; k < 4; ++k) x[k] = ptsN[(size_t)ic * 5 + 1 + k];

    float h1[32], h2[64], pf[32];
    dense<4, 32, true, true>(x, h1, W + O_PE1W, W + O_PE1B);
    dense<32, 64, true, true>(h1, h2, W + O_PE2W, W + O_PE2B);
    dense<64, 32, true, true>(h2, pf, W + O_PE3W, W + O_PE3B);

    if (valid) {
        int v = pv[i];
#pragma unroll
        for (int c = 0; c < 16; ++c) pf_u[(size_t)c * NPTS + i] = pack2(pf[2 * c], pf[2 * c + 1]);
        // pf >= 0 (post-relu), vox zero-init => int-bit atomicMax == float max; empty segments stay 0
#pragma unroll
        for (int c = 0; c < 32; ++c)
            atomicMax((int*)(vox + (size_t)v * 32 + c), __float_as_int(pf[c]));
    }
}

// ---------- K2: voxel MLP (32->32->32) + aux head ----------
__global__ __launch_bounds__(256) void k2_voxel(const float* __restrict__ vox,
                                                const float* __restrict__ W,
                                                const int* __restrict__ flags,
                                                unsigned* __restrict__ vf_u,
                                                void* __restrict__ outbase) {
    int v = blockIdx.x * 256 + threadIdx.x;
    if (v >= NVOX) return;
    int of32 = flags[0];
    float in[32];
#pragma unroll
    for (int c = 0; c < 32; ++c) in[c] = vox[(size_t)v * 32 + c];
    float v1[32], vf[32], a1[32], o[20];
    dense<32, 32, true, true>(in, v1, W + O_VE1W, W + O_VE1B);
    dense<32, 32, true, true>(v1, vf, W + O_VE2W, W + O_VE2B);
#pragma unroll
    for (int c = 0; c < 16; ++c) vf_u[(size_t)v * 16 + c] = pack2(vf[2 * c], vf[2 * c + 1]);
    dense<32, 32, true, true>(v1, a1, W + O_AUX1W, W + O_AUX1B);
    dense<32, 20, false, false>(a1, o, W + O_AUX2W, nullptr);
    if (of32) {
        float* auxf = (float*)outbase + (size_t)NPTS * NCLS + (size_t)v * NCLS;
#pragma unroll
        for (int t = 0; t < NCLS; ++t) auxf[t] = o[t];
    } else {
        unsigned* auxu = (unsigned*)((bf16*)outbase + (size_t)NPTS * NCLS);
#pragma unroll
        for (int t = 0; t < 10; ++t) auxu[(size_t)v * 10 + t] = pack2(o[2 * t], o[2 * t + 1]);
    }
}

// ---------- K3: fused layer + per-batch sums ----------
__global__ __launch_bounds__(256) void k3_sum(const int* __restrict__ bid,
                                              const int* __restrict__ pv,
                                              const unsigned* __restrict__ pf_u,
                                              const uint4* __restrict__ vf_q,
                                              const float* __restrict__ W,
                                              float* __restrict__ bsum,
                                              float* __restrict__ bcnt) {
    int i = blockIdx.x * 256 + threadIdx.x;
    bool valid = i < NPTS;
    int ic = valid ? i : NPTS - 1;
    int b = bid[ic];

    float cat[64];  // [pvf(32) | pf(32)]
    int vx = pv[ic];
#pragma unroll
    for (int t = 0; t < 4; ++t) {
        uint4 q = vf_q[(size_t)vx * 4 + t];
        unpack2(q.x, cat[8 * t + 0], cat[8 * t + 1]);
        unpack2(q.y, cat[8 * t + 2], cat[8 * t + 3]);
        unpack2(q.z, cat[8 * t + 4], cat[8 * t + 5]);
        unpack2(q.w, cat[8 * t + 6], cat[8 * t + 7]);
    }
#pragma unroll
    for (int c = 0; c < 16; ++c) unpack2(pf_u[(size_t)c * NPTS + ic], cat[32 + 2 * c], cat[32 + 2 * c + 1]);

    float f[64];
    dense<64, 64, true, true>(cat, f, W + O_FUW, W + O_FUB);
    if (!valid) {
#pragma unroll
        for (int j = 0; j < 64; ++j) f[j] = 0.f;
    }

    __shared__ int sb0, sflag;
    __shared__ float sw[4][64];
    if (threadIdx.x == 0) { sb0 = b; sflag = 1; }
    __syncthreads();
    if (valid && b != sb0) sflag = 0;
    __syncthreads();

    int wv = threadIdx.x >> 6, ln = threadIdx.x & 63;
    if (sflag) {  // block-uniform batch (all but ~3 blocks, sorted batch ids)
#pragma unroll
        for (int j = 0; j < 64; ++j) {
            float s = f[j];
            s += __shfl_xor(s, 1);  s += __shfl_xor(s, 2);  s += __shfl_xor(s, 4);
            s += __shfl_xor(s, 8);  s += __shfl_xor(s, 16); s += __shfl_xor(s, 32);
            if (ln == 0) sw[wv][j] = s;
        }
        __syncthreads();
        if (threadIdx.x < 64) {
            float t = sw[0][threadIdx.x] + sw[1][threadIdx.x] + sw[2][threadIdx.x] + sw[3][threadIdx.x];
            atomicAdd(&bsum[sb0 * 64 + threadIdx.x], t);
        }
        if (threadIdx.x == 0) {
            int start = blockIdx.x * 256;
            int vc = NPTS - start; if (vc > 256) vc = 256;
            atomicAdd(&bcnt[sb0], (float)vc);
        }
    } else {
        if (valid) {
#pragma unroll
            for (int j = 0; j < 64; ++j) atomicAdd(&bsum[b * 64 + j], f[j]);
            atomicAdd(&bcnt[b], 1.f);
        }
    }
}

// ---------- K4: SE gate ----------
__global__ void k4_gate(const float* __restrict__ bsum, const float* __restrict__ bcnt,
                        const float* __restrict__ W, float* __restrict__ gate) {
    __shared__ float m[4][64];
    __shared__ float hid[4][4];
    int tid = threadIdx.x, b = tid >> 6, c = tid & 63;
    m[b][c] = bsum[tid] / fmaxf(bcnt[b], 1.f);
    __syncthreads();
    if (c < 4) {
        const float* w = W + O_SE1W;
        float a = (W + O_SE1B)[c];
        for (int k = 0; k < 64; ++k) a = fmaf(m[b][k], w[k * 4 + c], a);
        hid[b][c] = fmaxf(a, 0.f);
    }
    __syncthreads();
    const float* w2 = W + O_SE2W;
    float g = (W + O_SE2B)[c];
#pragma unroll
    for (int h = 0; h < 4; ++h) g = fmaf(hid[b][h], w2[h * 64 + c], g);
    gate[tid] = 1.f + 1.f / (1.f + expf(-g));   // (1 + sigmoid)
}

// ---------- K5: recompute fused, gate, classify ----------
__global__ __launch_bounds__(256) void k5_out(const int* __restrict__ bid,
                                              const int* __restrict__ pv,
                                              const unsigned* __restrict__ pf_u,
                                              const uint4* __restrict__ vf_q,
                                              const float* __restrict__ W,
                                              const float* __restrict__ gate,
                                              const int* __restrict__ flags,
                                              void* __restrict__ out) {
    __shared__ float sg[256];
    sg[threadIdx.x] = gate[threadIdx.x];
    __syncthreads();
    int i = blockIdx.x * 256 + threadIdx.x;
    if (i >= NPTS) return;
    int of32 = flags[0];
    int b = bid[i];

    float cat[64];
    int vx = pv[i];
#pragma unroll
    for (int t = 0; t < 4; ++t) {
        uint4 q = vf_q[(size_t)vx * 4 + t];
        unpack2(q.x, cat[8 * t + 0], cat[8 * t + 1]);
        unpack2(q.y, cat[8 * t + 2], cat[8 * t + 3]);
        unpack2(q.z, cat[8 * t + 4], cat[8 * t + 5]);
        unpack2(q.w, cat[8 * t + 6], cat[8 * t + 7]);
    }
#pragma unroll
    for (int c = 0; c < 16; ++c) unpack2(pf_u[(size_t)c * NPTS + i], cat[32 + 2 * c], cat[32 + 2 * c + 1]);

    float f[64];
    {
        const float* fw = W + O_FUW; const float* fb = W + O_FUB;
#pragma unroll
        for (int j = 0; j < 64; ++j) {
            float a = fb[j];
#pragma unroll
            for (int k = 0; k < 64; ++k) a = fmaf(cat[k], fw[k * 64 + j], a);
            f[j] = fmaxf(a, 0.f) * sg[b * 64 + j];
        }
    }
    float h[32], o[20];
    dense<64, 32, true, true>(f, h, W + O_CLS1W, W + O_CLS1B);
    dense<32, 20, false, false>(h, o, W + O_CLS2W, nullptr);
    if (of32) {
        float* of = (float*)out + (size_t)i * NCLS;
#pragma unroll
        for (int t = 0; t < NCLS; ++t) of[t] = o[t];
    } else {
        unsigned* outu = (unsigned*)out;
#pragma unroll
        for (int t = 0; t < 10; ++t) outu[(size_t)i * 10 + t] = pack2(o[2 * t], o[2 * t + 1]);
    }
}

extern "C" void kernel_launch(void* const* d_in, const int* in_sizes, int n_in,
                              void* d_out, int out_size, void* d_ws, size_t ws_size,
                              hipStream_t stream) {
    WPtrs p;
    p.pe_w1 = d_in[2];  p.pe_g1 = d_in[3];  p.pe_b1 = d_in[4];
    p.pe_w2 = d_in[5];  p.pe_g2 = d_in[6];  p.pe_b2 = d_in[7];
    p.pe_w3 = d_in[8];  p.pe_g3 = d_in[9];  p.pe_b3 = d_in[10];
    p.ve_w1 = d_in[11]; p.ve_g1 = d_in[12]; p.ve_b1 = d_in[13];
    p.ve_w2 = d_in[14]; p.ve_g2 = d_in[15]; p.ve_b2 = d_in[16];
    p.fu_w  = d_in[17]; p.fu_g  = d_in[18]; p.fu_b  = d_in[19];
    p.se_w1 = d_in[20]; p.se_b1 = d_in[21];
    p.se_w2 = d_in[22]; p.se_b2 = d_in[23];
    p.cls_w1 = d_in[24]; p.cls_g1 = d_in[25]; p.cls_b1 = d_in[26];
    p.cls_w2 = d_in[27];
    p.aux_w1 = d_in[28]; p.aux_g1 = d_in[29]; p.aux_b1 = d_in[30];
    p.aux_w2 = d_in[31];

    float* base = (float*)d_ws;
    float* ptsN = base + L_PTS;
    int*   pvN  = (int*)(base + L_PV);
    int*   bidN = (int*)(base + L_BID);
    float* vox  = base + L_VOX;
    float* bsum = base + L_BSUM;
    float* bcnt = base + L_BCNT;
    float* gate = base + L_GATE;
    int*   flags = (int*)(base + L_FLAG);
    float* W    = base + L_W;
    unsigned* vf_u = (unsigned*)(base + L_VFU);
    unsigned* pf_u = (unsigned*)(base + L_PFU);

    // zero vox + bsum + bcnt (contiguous)
    hipMemsetAsync(vox, 0, ((size_t)NVOX * 32 + 260) * sizeof(float), stream);
    k0_detect<<<1, 64, 0, stream>>>((const unsigned short*)d_in[0], (const unsigned*)d_in[1], flags);
    k0_norm<<<19532, 256, 0, stream>>>(d_in[0], d_in[1], flags, ptsN, pvN, bidN);
    k0_prep<<<1, 256, 0, stream>>>(p, flags, W);
    k1_point<<<(NPTS + 255) / 256, 256, 0, stream>>>(ptsN, pvN, W, pf_u, vox);
    k2_voxel<<<(NVOX + 255) / 256, 256, 0, stream>>>(vox, W, flags, vf_u, d_out);
    k3_sum<<<(NPTS + 255) / 256, 256, 0, stream>>>(bidN, pvN, pf_u, (const uint4*)vf_u, W, bsum, bcnt);
    k4_gate<<<1, 256, 0, stream>>>(bsum, bcnt, W, gate);
    k5_out<<<(NPTS + 255) / 256, 256, 0, stream>>>(bidN, pvN, pf_u, (const uint4*)vf_u, W, gate, flags, d_out);
}

// Round 3
// 1252.765 us; speedup vs baseline: 1.8781x; 1.8781x over previous
//
#include <hip/hip_runtime.h>
#include <hip/hip_bf16.h>

#define NPTS 1000000
#define NVOX 200000
#define NCLS 20

typedef __hip_bfloat16 bf16;

// ---------- workspace layout (fp32 words) ----------
constexpr size_t L_PTSC = 0;                          // N float4 coords
constexpr size_t L_PV   = L_PTSC + (size_t)NPTS * 4;  // N int32 voxel ids
constexpr size_t L_BID  = L_PV + NPTS;                // N int32 batch ids
constexpr size_t L_CNT  = L_BID + NPTS;               // V counts (zero)
constexpr size_t L_BSUM = L_CNT + NVOX;               // 256 (zero)
constexpr size_t L_BCNT = L_BSUM + 256;               // 4 (zero)
constexpr size_t L_GATE = L_BCNT + 4;                 // 256
constexpr size_t L_FLAG = L_GATE + 256;               // 4
constexpr size_t L_OFFS = L_FLAG + 4;                 // V
constexpr size_t L_OFFW = L_OFFS + NVOX;              // V (scatter cursor)
constexpr size_t L_BS1  = L_OFFW + NVOX;              // 256 block sums
constexpr size_t L_BB   = L_BS1 + 256;                // 256 block bases
constexpr size_t L_IDX  = L_BB + 256;                 // N sorted point ids
constexpr size_t L_W    = L_IDX + NPTS;               // folded weights
// weight offsets inside W
constexpr int O_PE1W = 0;      constexpr int O_PE1B = 128;
constexpr int O_PE2W = 160;    constexpr int O_PE2B = 2208;
constexpr int O_PE3W = 2272;   constexpr int O_PE3B = 4320;
constexpr int O_VE1W = 4352;   constexpr int O_VE1B = 5376;
constexpr int O_VE2W = 5408;   constexpr int O_VE2B = 6432;
constexpr int O_FUW  = 6464;   constexpr int O_FUB  = 10560;
constexpr int O_SE1W = 10624;  constexpr int O_SE1B = 10880;
constexpr int O_SE2W = 10884;  constexpr int O_SE2B = 11140;
constexpr int O_CLS1W = 11204; constexpr int O_CLS1B = 13252;
constexpr int O_CLS2W = 13284;
constexpr int O_AUX1W = 13924; constexpr int O_AUX1B = 14948;
constexpr int O_AUX2W = 14980;
constexpr int W_TOTAL = 15620;
constexpr size_t L_VFU = L_W + W_TOTAL;               // V*16 packed bf16 pairs
constexpr size_t L_PFQ = L_VFU + (size_t)NVOX * 16;   // N*16 packed bf16 pairs (row-major, 64B/pt)
static_assert(L_VFU % 4 == 0, "vf 16B alignment");
static_assert(L_PFQ % 4 == 0, "pf 16B alignment");

static __device__ __forceinline__ float b2f(bf16 v) { return __bfloat162float(v); }
static __device__ __forceinline__ unsigned short f2us(float f) {
    unsigned u = __float_as_uint(f);
    u += 0x7fffu + ((u >> 16) & 1u);
    return (unsigned short)(u >> 16);
}
static __device__ __forceinline__ unsigned pack2(float a, float b) {
    return (unsigned)f2us(a) | ((unsigned)f2us(b) << 16);
}
static __device__ __forceinline__ void unpack2(unsigned u, float& a, float& b) {
    a = __uint_as_float(u << 16);
    b = __uint_as_float(u & 0xffff0000u);
}
static __device__ __forceinline__ float rdf(const void* p, size_t idx, int fp32) {
    return fp32 ? ((const float*)p)[idx] : b2f(((const bf16*)p)[idx]);
}

template <int K, int M, bool RELU, bool BIAS>
static __device__ __forceinline__ void dense(const float* __restrict__ x, float* __restrict__ y,
                                             const float* __restrict__ w, const float* __restrict__ b) {
#pragma unroll
    for (int j = 0; j < M; ++j) {
        float a = BIAS ? b[j] : 0.f;
#pragma unroll
        for (int k = 0; k < K; ++k) a = fmaf(x[k], w[k * M + j], a);
        y[j] = RELU ? fmaxf(a, 0.f) : a;
    }
}

// block-wide exclusive scan of one int per thread (256 threads)
static __device__ __forceinline__ int block_excl_scan(int v, int t) {
    __shared__ int sh[2][256];
    int cur = 0;
    sh[0][t] = v; __syncthreads();
#pragma unroll
    for (int off = 1; off < 256; off <<= 1) {
        int val = sh[cur][t];
        if (t >= off) val += sh[cur][t - off];
        sh[cur ^ 1][t] = val; __syncthreads();
        cur ^= 1;
    }
    return sh[cur][t] - v;
}

// ---------- K0a: detect input dtypes from data ----------
__global__ void k0_detect(const unsigned short* __restrict__ ptsu,
                          const unsigned* __restrict__ pvu, int* __restrict__ flags) {
    if (threadIdx.x == 0) {
        int fp32 = (ptsu[1] == 0 && ptsu[11] == 0) ? 1 : 0;     // high halves of 0.0f batch ids
        int i64 = (pvu[1] == 0 && pvu[3] == 0 && pvu[5] == 0 && pvu[7] == 0) ? 1 : 0;
        flags[0] = fp32;
        flags[1] = i64;
    }
}

// ---------- K0b: normalize points/ids + voxel histogram ----------
__global__ __launch_bounds__(256) void k0_norm(const void* __restrict__ pts_raw,
                                               const void* __restrict__ pv_raw,
                                               const int* __restrict__ flags,
                                               float4* __restrict__ ptsC,
                                               int* __restrict__ pvN,
                                               int* __restrict__ bidN,
                                               int* __restrict__ cnt) {
    int i = blockIdx.x * 256 + threadIdx.x;
    if (i >= NPTS) return;
    int fp32 = flags[0], i64 = flags[1];
    float4 c;
    c.x = rdf(pts_raw, (size_t)i * 5 + 1, fp32);
    c.y = rdf(pts_raw, (size_t)i * 5 + 2, fp32);
    c.z = rdf(pts_raw, (size_t)i * 5 + 3, fp32);
    c.w = rdf(pts_raw, (size_t)i * 5 + 4, fp32);
    ptsC[i] = c;
    bidN[i] = (int)rdf(pts_raw, (size_t)i * 5, fp32);
    int v = i64 ? (int)((const long long*)pv_raw)[i] : ((const int*)pv_raw)[i];
    pvN[i] = v;
    atomicAdd(&cnt[v], 1);
}

// ---------- K0c: fold BN into weights ----------
struct WPtrs {
    const void *pe_w1, *pe_g1, *pe_b1, *pe_w2, *pe_g2, *pe_b2, *pe_w3, *pe_g3, *pe_b3;
    const void *ve_w1, *ve_g1, *ve_b1, *ve_w2, *ve_g2, *ve_b2;
    const void *fu_w, *fu_g, *fu_b;
    const void *se_w1, *se_b1, *se_w2, *se_b2;
    const void *cls_w1, *cls_g1, *cls_b1, *cls_w2;
    const void *aux_w1, *aux_g1, *aux_b1, *aux_w2;
};

static __device__ void foldw(float* d, const void* w, const void* g, int K, int M, int fp32) {
    const float INV = 0.9999950000374997f;  // 1/sqrt(1+1e-5)
    for (int idx = threadIdx.x; idx < K * M; idx += 256)
        d[idx] = rdf(w, idx, fp32) * (rdf(g, idx % M, fp32) * INV);
}
static __device__ void cpv(float* d, const void* s, int n, int fp32) {
    for (int idx = threadIdx.x; idx < n; idx += 256) d[idx] = rdf(s, idx, fp32);
}

__global__ void k0_prep(WPtrs p, const int* __restrict__ flags, float* __restrict__ W) {
    int f = flags[0];
    foldw(W + O_PE1W, p.pe_w1, p.pe_g1, 4, 32, f);   cpv(W + O_PE1B, p.pe_b1, 32, f);
    foldw(W + O_PE2W, p.pe_w2, p.pe_g2, 32, 64, f);  cpv(W + O_PE2B, p.pe_b2, 64, f);
    foldw(W + O_PE3W, p.pe_w3, p.pe_g3, 64, 32, f);  cpv(W + O_PE3B, p.pe_b3, 32, f);
    foldw(W + O_VE1W, p.ve_w1, p.ve_g1, 32, 32, f);  cpv(W + O_VE1B, p.ve_b1, 32, f);
    foldw(W + O_VE2W, p.ve_w2, p.ve_g2, 32, 32, f);  cpv(W + O_VE2B, p.ve_b2, 32, f);
    foldw(W + O_FUW,  p.fu_w,  p.fu_g,  64, 64, f);  cpv(W + O_FUB,  p.fu_b, 64, f);
    cpv(W + O_SE1W, p.se_w1, 256, f);  cpv(W + O_SE1B, p.se_b1, 4, f);
    cpv(W + O_SE2W, p.se_w2, 256, f);  cpv(W + O_SE2B, p.se_b2, 64, f);
    foldw(W + O_CLS1W, p.cls_w1, p.cls_g1, 64, 32, f); cpv(W + O_CLS1B, p.cls_b1, 32, f);
    cpv(W + O_CLS2W, p.cls_w2, 640, f);
    foldw(W + O_AUX1W, p.aux_w1, p.aux_g1, 32, 32, f); cpv(W + O_AUX1B, p.aux_b1, 32, f);
    cpv(W + O_AUX2W, p.aux_w2, 640, f);
}

// ---------- counting-sort scan (3 small kernels, chunk=1024/block) ----------
__global__ __launch_bounds__(256) void k_scan1(const int* __restrict__ cnt, int* __restrict__ bs) {
    int t = threadIdx.x;
    int base = blockIdx.x * 1024 + t * 4;
    int s = 0;
#pragma unroll
    for (int k = 0; k < 4; ++k) { int idx = base + k; if (idx < NVOX) s += cnt[idx]; }
    __shared__ int red[256];
    red[t] = s; __syncthreads();
    for (int off = 128; off > 0; off >>= 1) { if (t < off) red[t] += red[t + off]; __syncthreads(); }
    if (t == 0) bs[blockIdx.x] = red[0];
}

__global__ __launch_bounds__(256) void k_scan2(const int* __restrict__ bs, int* __restrict__ bb, int nb) {
    int t = threadIdx.x;
    int v = (t < nb) ? bs[t] : 0;
    int e = block_excl_scan(v, t);
    bb[t] = e;
}

__global__ __launch_bounds__(256) void k_scan3(const int* __restrict__ cnt, const int* __restrict__ bb,
                                               int* __restrict__ offs, int* __restrict__ offw) {
    int t = threadIdx.x;
    int base = blockIdx.x * 1024 + t * 4;
    int c[4]; int s = 0;
#pragma unroll
    for (int k = 0; k < 4; ++k) { int idx = base + k; c[k] = (idx < NVOX) ? cnt[idx] : 0; s += c[k]; }
    int run = bb[blockIdx.x] + block_excl_scan(s, t);
#pragma unroll
    for (int k = 0; k < 4; ++k) {
        int idx = base + k;
        if (idx < NVOX) { offs[idx] = run; offw[idx] = run; run += c[k]; }
    }
}

__global__ __launch_bounds__(256) void k_scatter(const int* __restrict__ pvN,
                                                 int* __restrict__ offw, int* __restrict__ idx_sorted) {
    int i = blockIdx.x * 256 + threadIdx.x;
    if (i >= NPTS) return;
    int pos = atomicAdd(&offw[pvN[i]], 1);
    idx_sorted[pos] = i;
}

// ---------- K1: point MLP (4->32->64->32), no atomics ----------
__global__ __launch_bounds__(256) void k1_point(const float4* __restrict__ ptsC,
                                                const float* __restrict__ W,
                                                uint4* __restrict__ pf_q) {
    int i = blockIdx.x * 256 + threadIdx.x;
    if (i >= NPTS) return;
    float4 c = ptsC[i];
    float x[4] = {c.x, c.y, c.z, c.w};
    float h1[32], h2[64], pf[32];
    dense<4, 32, true, true>(x, h1, W + O_PE1W, W + O_PE1B);
    dense<32, 64, true, true>(h1, h2, W + O_PE2W, W + O_PE2B);
    dense<64, 32, true, true>(h2, pf, W + O_PE3W, W + O_PE3B);
#pragma unroll
    for (int t = 0; t < 4; ++t)
        pf_q[(size_t)i * 4 + t] = make_uint4(pack2(pf[8*t+0], pf[8*t+1]), pack2(pf[8*t+2], pf[8*t+3]),
                                             pack2(pf[8*t+4], pf[8*t+5]), pack2(pf[8*t+6], pf[8*t+7]));
}

// ---------- K2: per-voxel max gather + voxel MLP + aux head ----------
__global__ __launch_bounds__(256) void k_voxmlp(const int* __restrict__ offs, const int* __restrict__ cnt,
                                                const int* __restrict__ idx_sorted,
                                                const uint4* __restrict__ pf_q,
                                                const float* __restrict__ W,
                                                const int* __restrict__ flags,
                                                unsigned* __restrict__ vf_u,
                                                void* __restrict__ outbase) {
    int v = blockIdx.x * 256 + threadIdx.x;
    if (v >= NVOX) return;
    int of32 = flags[0];
    float mx[32];
#pragma unroll
    for (int c = 0; c < 32; ++c) mx[c] = 0.f;   // empty segments -> 0 (matches where(isfinite))
    int s = offs[v], n = cnt[v];
    for (int p = 0; p < n; ++p) {
        int j = idx_sorted[s + p];
#pragma unroll
        for (int t = 0; t < 4; ++t) {
            uint4 q = pf_q[(size_t)j * 4 + t];
            float a, b;
            unpack2(q.x, a, b); mx[8*t+0] = fmaxf(mx[8*t+0], a); mx[8*t+1] = fmaxf(mx[8*t+1], b);
            unpack2(q.y, a, b); mx[8*t+2] = fmaxf(mx[8*t+2], a); mx[8*t+3] = fmaxf(mx[8*t+3], b);
            unpack2(q.z, a, b); mx[8*t+4] = fmaxf(mx[8*t+4], a); mx[8*t+5] = fmaxf(mx[8*t+5], b);
            unpack2(q.w, a, b); mx[8*t+6] = fmaxf(mx[8*t+6], a); mx[8*t+7] = fmaxf(mx[8*t+7], b);
        }
    }
    float v1[32], vf[32], a1[32], o[20];
    dense<32, 32, true, true>(mx, v1, W + O_VE1W, W + O_VE1B);
    dense<32, 32, true, true>(v1, vf, W + O_VE2W, W + O_VE2B);
#pragma unroll
    for (int c = 0; c < 16; ++c) vf_u[(size_t)v * 16 + c] = pack2(vf[2*c], vf[2*c+1]);
    dense<32, 32, true, true>(v1, a1, W + O_AUX1W, W + O_AUX1B);
    dense<32, 20, false, false>(a1, o, W + O_AUX2W, nullptr);
    if (of32) {
        float* auxf = (float*)outbase + (size_t)NPTS * NCLS + (size_t)v * NCLS;
#pragma unroll
        for (int t = 0; t < NCLS; ++t) auxf[t] = o[t];
    } else {
        unsigned* auxu = (unsigned*)((bf16*)outbase + (size_t)NPTS * NCLS);
#pragma unroll
        for (int t = 0; t < 10; ++t) auxu[(size_t)v * 10 + t] = pack2(o[2*t], o[2*t+1]);
    }
}

// ---------- K3: fused layer + per-batch sums ----------
__global__ __launch_bounds__(256) void k3_sum(const int* __restrict__ bid,
                                              const int* __restrict__ pv,
                                              const uint4* __restrict__ pf_q,
                                              const uint4* __restrict__ vf_q,
                                              const float* __restrict__ W,
                                              float* __restrict__ bsum,
                                              float* __restrict__ bcnt) {
    int i = blockIdx.x * 256 + threadIdx.x;
    bool valid = i < NPTS;
    int ic = valid ? i : NPTS - 1;
    int b = bid[ic];

    float cat[64];  // [pvf(32) | pf(32)]
    int vx = pv[ic];
#pragma unroll
    for (int t = 0; t < 4; ++t) {
        uint4 q = vf_q[(size_t)vx * 4 + t];
        unpack2(q.x, cat[8*t+0], cat[8*t+1]);
        unpack2(q.y, cat[8*t+2], cat[8*t+3]);
        unpack2(q.z, cat[8*t+4], cat[8*t+5]);
        unpack2(q.w, cat[8*t+6], cat[8*t+7]);
    }
#pragma unroll
    for (int t = 0; t < 4; ++t) {
        uint4 q = pf_q[(size_t)ic * 4 + t];
        unpack2(q.x, cat[32+8*t+0], cat[32+8*t+1]);
        unpack2(q.y, cat[32+8*t+2], cat[32+8*t+3]);
        unpack2(q.z, cat[32+8*t+4], cat[32+8*t+5]);
        unpack2(q.w, cat[32+8*t+6], cat[32+8*t+7]);
    }

    float f[64];
    dense<64, 64, true, true>(cat, f, W + O_FUW, W + O_FUB);
    if (!valid) {
#pragma unroll
        for (int j = 0; j < 64; ++j) f[j] = 0.f;
    }

    __shared__ int sb0, sflag;
    __shared__ float sw[4][64];
    if (threadIdx.x == 0) { sb0 = b; sflag = 1; }
    __syncthreads();
    if (valid && b != sb0) sflag = 0;
    __syncthreads();

    int wv = threadIdx.x >> 6, ln = threadIdx.x & 63;
    if (sflag) {  // block-uniform batch (sorted batch ids; all but ~3 blocks)
#pragma unroll
        for (int j = 0; j < 64; ++j) {
            float s = f[j];
            s += __shfl_xor(s, 1);  s += __shfl_xor(s, 2);  s += __shfl_xor(s, 4);
            s += __shfl_xor(s, 8);  s += __shfl_xor(s, 16); s += __shfl_xor(s, 32);
            if (ln == 0) sw[wv][j] = s;
        }
        __syncthreads();
        if (threadIdx.x < 64) {
            float t = sw[0][threadIdx.x] + sw[1][threadIdx.x] + sw[2][threadIdx.x] + sw[3][threadIdx.x];
            atomicAdd(&bsum[sb0 * 64 + threadIdx.x], t);
        }
        if (threadIdx.x == 0) {
            int start = blockIdx.x * 256;
            int vc = NPTS - start; if (vc > 256) vc = 256;
            atomicAdd(&bcnt[sb0], (float)vc);
        }
    } else {
        if (valid) {
#pragma unroll
            for (int j = 0; j < 64; ++j) atomicAdd(&bsum[b * 64 + j], f[j]);
            atomicAdd(&bcnt[b], 1.f);
        }
    }
}

// ---------- K4: SE gate ----------
__global__ void k4_gate(const float* __restrict__ bsum, const float* __restrict__ bcnt,
                        const float* __restrict__ W, float* __restrict__ gate) {
    __shared__ float m[4][64];
    __shared__ float hid[4][4];
    int tid = threadIdx.x, b = tid >> 6, c = tid & 63;
    m[b][c] = bsum[tid] / fmaxf(bcnt[b], 1.f);
    __syncthreads();
    if (c < 4) {
        const float* w = W + O_SE1W;
        float a = (W + O_SE1B)[c];
        for (int k = 0; k < 64; ++k) a = fmaf(m[b][k], w[k * 4 + c], a);
        hid[b][c] = fmaxf(a, 0.f);
    }
    __syncthreads();
    const float* w2 = W + O_SE2W;
    float g = (W + O_SE2B)[c];
#pragma unroll
    for (int h = 0; h < 4; ++h) g = fmaf(hid[b][h], w2[h * 64 + c], g);
    gate[tid] = 1.f + 1.f / (1.f + expf(-g));   // (1 + sigmoid)
}

// ---------- K5: recompute fused, gate, classify ----------
__global__ __launch_bounds__(256) void k5_out(const int* __restrict__ bid,
                                              const int* __restrict__ pv,
                                              const uint4* __restrict__ pf_q,
                                              const uint4* __restrict__ vf_q,
                                              const float* __restrict__ W,
                                              const float* __restrict__ gate,
                                              const int* __restrict__ flags,
                                              void* __restrict__ out) {
    __shared__ float sg[256];
    sg[threadIdx.x] = gate[threadIdx.x];
    __syncthreads();
    int i = blockIdx.x * 256 + threadIdx.x;
    if (i >= NPTS) return;
    int of32 = flags[0];
    int b = bid[i];

    float cat[64];
    int vx = pv[i];
#pragma unroll
    for (int t = 0; t < 4; ++t) {
        uint4 q = vf_q[(size_t)vx * 4 + t];
        unpack2(q.x, cat[8*t+0], cat[8*t+1]);
        unpack2(q.y, cat[8*t+2], cat[8*t+3]);
        unpack2(q.z, cat[8*t+4], cat[8*t+5]);
        unpack2(q.w, cat[8*t+6], cat[8*t+7]);
    }
#pragma unroll
    for (int t = 0; t < 4; ++t) {
        uint4 q = pf_q[(size_t)i * 4 + t];
        unpack2(q.x, cat[32+8*t+0], cat[32+8*t+1]);
        unpack2(q.y, cat[32+8*t+2], cat[32+8*t+3]);
        unpack2(q.z, cat[32+8*t+4], cat[32+8*t+5]);
        unpack2(q.w, cat[32+8*t+6], cat[32+8*t+7]);
    }

    float f[64];
    {
        const float* fw = W + O_FUW; const float* fb = W + O_FUB;
#pragma unroll
        for (int j = 0; j < 64; ++j) {
            float a = fb[j];
#pragma unroll
            for (int k = 0; k < 64; ++k) a = fmaf(cat[k], fw[k * 64 + j], a);
            f[j] = fmaxf(a, 0.f) * sg[b * 64 + j];
        }
    }
    float h[32], o[20];
    dense<64, 32, true, true>(f, h, W + O_CLS1W, W + O_CLS1B);
    dense<32, 20, false, false>(h, o, W + O_CLS2W, nullptr);
    if (of32) {
        float* of = (float*)out + (size_t)i * NCLS;
#pragma unroll
        for (int t = 0; t < NCLS; ++t) of[t] = o[t];
    } else {
        unsigned* outu = (unsigned*)out;
#pragma unroll
        for (int t = 0; t < 10; ++t) outu[(size_t)i * 10 + t] = pack2(o[2*t], o[2*t+1]);
    }
}

extern "C" void kernel_launch(void* const* d_in, const int* in_sizes, int n_in,
                              void* d_out, int out_size, void* d_ws, size_t ws_size,
                              hipStream_t stream) {
    WPtrs p;
    p.pe_w1 = d_in[2];  p.pe_g1 = d_in[3];  p.pe_b1 = d_in[4];
    p.pe_w2 = d_in[5];  p.pe_g2 = d_in[6];  p.pe_b2 = d_in[7];
    p.pe_w3 = d_in[8];  p.pe_g3 = d_in[9];  p.pe_b3 = d_in[10];
    p.ve_w1 = d_in[11]; p.ve_g1 = d_in[12]; p.ve_b1 = d_in[13];
    p.ve_w2 = d_in[14]; p.ve_g2 = d_in[15]; p.ve_b2 = d_in[16];
    p.fu_w  = d_in[17]; p.fu_g  = d_in[18]; p.fu_b  = d_in[19];
    p.se_w1 = d_in[20]; p.se_b1 = d_in[21];
    p.se_w2 = d_in[22]; p.se_b2 = d_in[23];
    p.cls_w1 = d_in[24]; p.cls_g1 = d_in[25]; p.cls_b1 = d_in[26];
    p.cls_w2 = d_in[27];
    p.aux_w1 = d_in[28]; p.aux_g1 = d_in[29]; p.aux_b1 = d_in[30];
    p.aux_w2 = d_in[31];

    float* base = (float*)d_ws;
    float4* ptsC = (float4*)(base + L_PTSC);
    int*   pvN  = (int*)(base + L_PV);
    int*   bidN = (int*)(base + L_BID);
    int*   cnt  = (int*)(base + L_CNT);
    float* bsum = base + L_BSUM;
    float* bcnt = base + L_BCNT;
    float* gate = base + L_GATE;
    int*   flags = (int*)(base + L_FLAG);
    int*   offs = (int*)(base + L_OFFS);
    int*   offw = (int*)(base + L_OFFW);
    int*   bs1  = (int*)(base + L_BS1);
    int*   bb   = (int*)(base + L_BB);
    int*   idxs = (int*)(base + L_IDX);
    float* W    = base + L_W;
    unsigned* vf_u = (unsigned*)(base + L_VFU);
    uint4* pf_q = (uint4*)(base + L_PFQ);

    constexpr int NBP = (NPTS + 255) / 256;       // point-grid blocks
    constexpr int NBV = (NVOX + 255) / 256;       // voxel-grid blocks
    constexpr int NBS = (NVOX + 1023) / 1024;     // scan blocks (196)

    // zero cnt + bsum + bcnt (contiguous)
    hipMemsetAsync(cnt, 0, (NVOX + 260) * sizeof(float), stream);
    k0_detect<<<1, 64, 0, stream>>>((const unsigned short*)d_in[0], (const unsigned*)d_in[1], flags);
    k0_norm<<<NBP, 256, 0, stream>>>(d_in[0], d_in[1], flags, ptsC, pvN, bidN, cnt);
    k0_prep<<<1, 256, 0, stream>>>(p, flags, W);
    k_scan1<<<NBS, 256, 0, stream>>>(cnt, bs1);
    k_scan2<<<1, 256, 0, stream>>>(bs1, bb, NBS);
    k_scan3<<<NBS, 256, 0, stream>>>(cnt, bb, offs, offw);
    k_scatter<<<NBP, 256, 0, stream>>>(pvN, offw, idxs);
    k1_point<<<NBP, 256, 0, stream>>>(ptsC, W, pf_q);
    k_voxmlp<<<NBV, 256, 0, stream>>>(offs, cnt, idxs, pf_q, W, flags, vf_u, d_out);
    k3_sum<<<NBP, 256, 0, stream>>>(bidN, pvN, pf_q, (const uint4*)vf_u, W, bsum, bcnt);
    k4_gate<<<1, 256, 0, stream>>>(bsum, bcnt, W, gate);
    k5_out<<<NBP, 256, 0, stream>>>(bidN, pvN, pf_q, (const uint4*)vf_u, W, gate, flags, d_out);
}

// Round 4
// 939.054 us; speedup vs baseline: 2.5055x; 1.3341x over previous
//
#include <hip/hip_runtime.h>
#include <hip/hip_bf16.h>

#define NPTS 1000000
#define NVOX 200000
#define NCLS 20

typedef __hip_bfloat16 bf16;
typedef __attribute__((ext_vector_type(8))) short bf16x8_t;
typedef __attribute__((ext_vector_type(4))) float f32x4_t;
#define MFMA16(a, b, c) __builtin_amdgcn_mfma_f32_16x16x32_bf16(a, b, c, 0, 0, 0)

// ---------- workspace layout (fp32 words) ----------
constexpr size_t L_PTSC = 0;                          // N float4 coords
constexpr size_t L_PV   = L_PTSC + (size_t)NPTS * 4;  // N int32 voxel ids
constexpr size_t L_BID  = L_PV + NPTS;                // N int32 batch ids
constexpr size_t L_CNT  = L_BID + NPTS;               // V counts (zero)
constexpr size_t L_BSUM = L_CNT + NVOX;               // 256 (zero)
constexpr size_t L_BCNT = L_BSUM + 256;               // 4 (zero)
constexpr size_t L_GATE = L_BCNT + 4;                 // 256
constexpr size_t L_FLAG = L_GATE + 256;               // 4
constexpr size_t L_OFFS = L_FLAG + 4;                 // V
constexpr size_t L_OFFW = L_OFFS + NVOX;              // V (scatter cursor)
constexpr size_t L_BS1  = L_OFFW + NVOX;              // 256 block sums
constexpr size_t L_BB   = L_BS1 + 256;                // 256 block bases
constexpr size_t L_IDX  = L_BB + 256;                 // N sorted point ids
constexpr size_t L_W    = L_IDX + NPTS;               // folded weights fp32
// weight offsets inside W
constexpr int O_PE1W = 0;      constexpr int O_PE1B = 128;
constexpr int O_PE2W = 160;    constexpr int O_PE2B = 2208;
constexpr int O_PE3W = 2272;   constexpr int O_PE3B = 4320;
constexpr int O_VE1W = 4352;   constexpr int O_VE1B = 5376;
constexpr int O_VE2W = 5408;   constexpr int O_VE2B = 6432;
constexpr int O_FUW  = 6464;   constexpr int O_FUB  = 10560;
constexpr int O_SE1W = 10624;  constexpr int O_SE1B = 10880;
constexpr int O_SE2W = 10884;  constexpr int O_SE2B = 11140;
constexpr int O_CLS1W = 11204; constexpr int O_CLS1B = 13252;
constexpr int O_CLS2W = 13284;
constexpr int O_AUX1W = 13924; constexpr int O_AUX1B = 14948;
constexpr int O_AUX2W = 14980;
constexpr int W_TOTAL = 15620;
constexpr size_t L_WT  = L_W + W_TOTAL;               // bf16 transposed weights: fu 4096 + cls1 2048 + cls2 1024 ushorts
static_assert(L_WT % 4 == 0, "WT 16B alignment");
constexpr size_t L_VFU = L_WT + (4096 + 2048 + 1024) / 2;   // V*16 packed bf16 pairs
constexpr size_t L_PFQ = L_VFU + (size_t)NVOX * 16;   // N*16 packed bf16 pairs (row-major, 64B/pt)
static_assert(L_VFU % 4 == 0, "vf 16B alignment");
static_assert(L_PFQ % 4 == 0, "pf 16B alignment");

static __device__ __forceinline__ float b2f(bf16 v) { return __bfloat162float(v); }
static __device__ __forceinline__ float us2f(unsigned short u) { return __uint_as_float((unsigned)u << 16); }
static __device__ __forceinline__ unsigned short f2us(float f) {
    unsigned u = __float_as_uint(f);
    u += 0x7fffu + ((u >> 16) & 1u);
    return (unsigned short)(u >> 16);
}
static __device__ __forceinline__ unsigned pack2(float a, float b) {
    return (unsigned)f2us(a) | ((unsigned)f2us(b) << 16);
}
static __device__ __forceinline__ void unpack2(unsigned u, float& a, float& b) {
    a = __uint_as_float(u << 16);
    b = __uint_as_float(u & 0xffff0000u);
}
static __device__ __forceinline__ float rdf(const void* p, size_t idx, int fp32) {
    return fp32 ? ((const float*)p)[idx] : b2f(((const bf16*)p)[idx]);
}

template <int K, int M, bool RELU, bool BIAS>
static __device__ __forceinline__ void dense(const float* __restrict__ x, float* __restrict__ y,
                                             const float* __restrict__ w, const float* __restrict__ b) {
#pragma unroll
    for (int j = 0; j < M; ++j) {
        float a = BIAS ? b[j] : 0.f;
#pragma unroll
        for (int k = 0; k < K; ++k) a = fmaf(x[k], w[k * M + j], a);
        y[j] = RELU ? fmaxf(a, 0.f) : a;
    }
}

// block-wide exclusive scan of one int per thread (256 threads)
static __device__ __forceinline__ int block_excl_scan(int v, int t) {
    __shared__ int sh[2][256];
    int cur = 0;
    sh[0][t] = v; __syncthreads();
#pragma unroll
    for (int off = 1; off < 256; off <<= 1) {
        int val = sh[cur][t];
        if (t >= off) val += sh[cur][t - off];
        sh[cur ^ 1][t] = val; __syncthreads();
        cur ^= 1;
    }
    return sh[cur][t] - v;
}

// ---------- K0a: detect input dtypes from data ----------
__global__ void k0_detect(const unsigned short* __restrict__ ptsu,
                          const unsigned* __restrict__ pvu, int* __restrict__ flags) {
    if (threadIdx.x == 0) {
        int fp32 = (ptsu[1] == 0 && ptsu[11] == 0) ? 1 : 0;     // high halves of 0.0f batch ids
        int i64 = (pvu[1] == 0 && pvu[3] == 0 && pvu[5] == 0 && pvu[7] == 0) ? 1 : 0;
        flags[0] = fp32;
        flags[1] = i64;
    }
}

// ---------- K0b: normalize points/ids + voxel histogram + batch counts ----------
__global__ __launch_bounds__(256) void k0_norm(const void* __restrict__ pts_raw,
                                               const void* __restrict__ pv_raw,
                                               const int* __restrict__ flags,
                                               float4* __restrict__ ptsC,
                                               int* __restrict__ pvN,
                                               int* __restrict__ bidN,
                                               int* __restrict__ cnt,
                                               float* __restrict__ bcnt) {
    int i = blockIdx.x * 256 + threadIdx.x;
    bool valid = i < NPTS;
    int fp32 = flags[0], i64 = flags[1];
    int b = 0;
    if (valid) {
        float4 c;
        c.x = rdf(pts_raw, (size_t)i * 5 + 1, fp32);
        c.y = rdf(pts_raw, (size_t)i * 5 + 2, fp32);
        c.z = rdf(pts_raw, (size_t)i * 5 + 3, fp32);
        c.w = rdf(pts_raw, (size_t)i * 5 + 4, fp32);
        ptsC[i] = c;
        b = (int)rdf(pts_raw, (size_t)i * 5, fp32);
        bidN[i] = b;
        int v = i64 ? (int)((const long long*)pv_raw)[i] : ((const int*)pv_raw)[i];
        pvN[i] = v;
        atomicAdd(&cnt[v], 1);
    }
    __shared__ int sb0, sflag;
    if (threadIdx.x == 0) { sb0 = b; sflag = 1; }
    __syncthreads();
    if (valid && b != sb0) sflag = 0;
    __syncthreads();
    if (sflag) {
        if (threadIdx.x == 0) {
            int vc = NPTS - blockIdx.x * 256; if (vc > 256) vc = 256;
            atomicAdd(&bcnt[sb0], (float)vc);
        }
    } else if (valid) {
        atomicAdd(&bcnt[b], 1.f);
    }
}

// ---------- K0c: fold BN into weights + build bf16 transposed weights ----------
struct WPtrs {
    const void *pe_w1, *pe_g1, *pe_b1, *pe_w2, *pe_g2, *pe_b2, *pe_w3, *pe_g3, *pe_b3;
    const void *ve_w1, *ve_g1, *ve_b1, *ve_w2, *ve_g2, *ve_b2;
    const void *fu_w, *fu_g, *fu_b;
    const void *se_w1, *se_b1, *se_w2, *se_b2;
    const void *cls_w1, *cls_g1, *cls_b1, *cls_w2;
    const void *aux_w1, *aux_g1, *aux_b1, *aux_w2;
};

static __device__ void foldw(float* d, const void* w, const void* g, int K, int M, int fp32) {
    const float INV = 0.9999950000374997f;  // 1/sqrt(1+1e-5)
    for (int idx = threadIdx.x; idx < K * M; idx += 256)
        d[idx] = rdf(w, idx, fp32) * (rdf(g, idx % M, fp32) * INV);
}
static __device__ void cpv(float* d, const void* s, int n, int fp32) {
    for (int idx = threadIdx.x; idx < n; idx += 256) d[idx] = rdf(s, idx, fp32);
}

__global__ void k0_prep(WPtrs p, const int* __restrict__ flags, float* __restrict__ W,
                        unsigned short* __restrict__ WT) {
    int f = flags[0];
    foldw(W + O_PE1W, p.pe_w1, p.pe_g1, 4, 32, f);   cpv(W + O_PE1B, p.pe_b1, 32, f);
    foldw(W + O_PE2W, p.pe_w2, p.pe_g2, 32, 64, f);  cpv(W + O_PE2B, p.pe_b2, 64, f);
    foldw(W + O_PE3W, p.pe_w3, p.pe_g3, 64, 32, f);  cpv(W + O_PE3B, p.pe_b3, 32, f);
    foldw(W + O_VE1W, p.ve_w1, p.ve_g1, 32, 32, f);  cpv(W + O_VE1B, p.ve_b1, 32, f);
    foldw(W + O_VE2W, p.ve_w2, p.ve_g2, 32, 32, f);  cpv(W + O_VE2B, p.ve_b2, 32, f);
    foldw(W + O_FUW,  p.fu_w,  p.fu_g,  64, 64, f);  cpv(W + O_FUB,  p.fu_b, 64, f);
    cpv(W + O_SE1W, p.se_w1, 256, f);  cpv(W + O_SE1B, p.se_b1, 4, f);
    cpv(W + O_SE2W, p.se_w2, 256, f);  cpv(W + O_SE2B, p.se_b2, 64, f);
    foldw(W + O_CLS1W, p.cls_w1, p.cls_g1, 64, 32, f); cpv(W + O_CLS1B, p.cls_b1, 32, f);
    cpv(W + O_CLS2W, p.cls_w2, 640, f);
    foldw(W + O_AUX1W, p.aux_w1, p.aux_g1, 32, 32, f); cpv(W + O_AUX1B, p.aux_b1, 32, f);
    cpv(W + O_AUX2W, p.aux_w2, 640, f);
    __syncthreads();
    // bf16 transposed copies for MFMA B-operands: WT[n][k]
    unsigned short* wtfu = WT;                 // [64][64]
    unsigned short* wtc1 = WT + 4096;          // [32][64]
    unsigned short* wtc2 = WT + 4096 + 2048;   // [32][32], rows >= 20 zero
    for (int idx = threadIdx.x; idx < 4096; idx += 256) {
        int n = idx >> 6, k = idx & 63;
        wtfu[idx] = f2us(W[O_FUW + k * 64 + n]);
    }
    for (int idx = threadIdx.x; idx < 2048; idx += 256) {
        int n = idx >> 6, k = idx & 63;
        wtc1[idx] = f2us(W[O_CLS1W + k * 32 + n]);
    }
    for (int idx = threadIdx.x; idx < 1024; idx += 256) {
        int n = idx >> 5, k = idx & 31;
        wtc2[idx] = (n < NCLS) ? f2us(W[O_CLS2W + k * NCLS + n]) : (unsigned short)0;
    }
}

// ---------- counting-sort scan (3 small kernels, chunk=1024/block) ----------
__global__ __launch_bounds__(256) void k_scan1(const int* __restrict__ cnt, int* __restrict__ bs) {
    int t = threadIdx.x;
    int base = blockIdx.x * 1024 + t * 4;
    int s = 0;
#pragma unroll
    for (int k = 0; k < 4; ++k) { int idx = base + k; if (idx < NVOX) s += cnt[idx]; }
    __shared__ int red[256];
    red[t] = s; __syncthreads();
    for (int off = 128; off > 0; off >>= 1) { if (t < off) red[t] += red[t + off]; __syncthreads(); }
    if (t == 0) bs[blockIdx.x] = red[0];
}

__global__ __launch_bounds__(256) void k_scan2(const int* __restrict__ bs, int* __restrict__ bb, int nb) {
    int t = threadIdx.x;
    int v = (t < nb) ? bs[t] : 0;
    int e = block_excl_scan(v, t);
    bb[t] = e;
}

__global__ __launch_bounds__(256) void k_scan3(const int* __restrict__ cnt, const int* __restrict__ bb,
                                               int* __restrict__ offs, int* __restrict__ offw) {
    int t = threadIdx.x;
    int base = blockIdx.x * 1024 + t * 4;
    int c[4]; int s = 0;
#pragma unroll
    for (int k = 0; k < 4; ++k) { int idx = base + k; c[k] = (idx < NVOX) ? cnt[idx] : 0; s += c[k]; }
    int run = bb[blockIdx.x] + block_excl_scan(s, t);
#pragma unroll
    for (int k = 0; k < 4; ++k) {
        int idx = base + k;
        if (idx < NVOX) { offs[idx] = run; offw[idx] = run; run += c[k]; }
    }
}

__global__ __launch_bounds__(256) void k_scatter(const int* __restrict__ pvN,
                                                 int* __restrict__ offw, int* __restrict__ idx_sorted) {
    int i = blockIdx.x * 256 + threadIdx.x;
    if (i >= NPTS) return;
    int pos = atomicAdd(&offw[pvN[i]], 1);
    idx_sorted[pos] = i;
}

// ---------- K1: point MLP (4->32->64->32) ----------
__global__ __launch_bounds__(256) void k1_point(const float4* __restrict__ ptsC,
                                                const float* __restrict__ W,
                                                uint4* __restrict__ pf_q) {
    int i = blockIdx.x * 256 + threadIdx.x;
    if (i >= NPTS) return;
    float4 c = ptsC[i];
    float x[4] = {c.x, c.y, c.z, c.w};
    float h1[32], h2[64], pf[32];
    dense<4, 32, true, true>(x, h1, W + O_PE1W, W + O_PE1B);
    dense<32, 64, true, true>(h1, h2, W + O_PE2W, W + O_PE2B);
    dense<64, 32, true, true>(h2, pf, W + O_PE3W, W + O_PE3B);
#pragma unroll
    for (int t = 0; t < 4; ++t)
        pf_q[(size_t)i * 4 + t] = make_uint4(pack2(pf[8*t+0], pf[8*t+1]), pack2(pf[8*t+2], pf[8*t+3]),
                                             pack2(pf[8*t+4], pf[8*t+5]), pack2(pf[8*t+6], pf[8*t+7]));
}

// ---------- K2: per-voxel max gather + voxel MLP + aux head ----------
__global__ __launch_bounds__(256) void k_voxmlp(const int* __restrict__ offs, const int* __restrict__ cnt,
                                                const int* __restrict__ idx_sorted,
                                                const uint4* __restrict__ pf_q,
                                                const float* __restrict__ W,
                                                const int* __restrict__ flags,
                                                unsigned* __restrict__ vf_u,
                                                void* __restrict__ outbase) {
    int v = blockIdx.x * 256 + threadIdx.x;
    if (v >= NVOX) return;
    int of32 = flags[0];
    float mx[32];
#pragma unroll
    for (int c = 0; c < 32; ++c) mx[c] = 0.f;   // empty segments -> 0 (matches where(isfinite))
    int s = offs[v], n = cnt[v];
    for (int p = 0; p < n; ++p) {
        int j = idx_sorted[s + p];
#pragma unroll
        for (int t = 0; t < 4; ++t) {
            uint4 q = pf_q[(size_t)j * 4 + t];
            float a, b;
            unpack2(q.x, a, b); mx[8*t+0] = fmaxf(mx[8*t+0], a); mx[8*t+1] = fmaxf(mx[8*t+1], b);
            unpack2(q.y, a, b); mx[8*t+2] = fmaxf(mx[8*t+2], a); mx[8*t+3] = fmaxf(mx[8*t+3], b);
            unpack2(q.z, a, b); mx[8*t+4] = fmaxf(mx[8*t+4], a); mx[8*t+5] = fmaxf(mx[8*t+5], b);
            unpack2(q.w, a, b); mx[8*t+6] = fmaxf(mx[8*t+6], a); mx[8*t+7] = fmaxf(mx[8*t+7], b);
        }
    }
    float v1[32], vf[32], a1[32], o[20];
    dense<32, 32, true, true>(mx, v1, W + O_VE1W, W + O_VE1B);
    dense<32, 32, true, true>(v1, vf, W + O_VE2W, W + O_VE2B);
#pragma unroll
    for (int c = 0; c < 16; ++c) vf_u[(size_t)v * 16 + c] = pack2(vf[2*c], vf[2*c+1]);
    dense<32, 32, true, true>(v1, a1, W + O_AUX1W, W + O_AUX1B);
    dense<32, 20, false, false>(a1, o, W + O_AUX2W, nullptr);
    if (of32) {
        float* auxf = (float*)outbase + (size_t)NPTS * NCLS + (size_t)v * NCLS;
#pragma unroll
        for (int t = 0; t < NCLS; ++t) auxf[t] = o[t];
    } else {
        unsigned* auxu = (unsigned*)((bf16*)outbase + (size_t)NPTS * NCLS);
#pragma unroll
        for (int t = 0; t < 10; ++t) auxu[(size_t)v * 10 + t] = pack2(o[2*t], o[2*t+1]);
    }
}

// ---------- shared MFMA helpers (64 points per block, 16 per wave) ----------
static __device__ __forceinline__ void stage_cat(unsigned short (*cat)[72], const int* svx,
                                                 const uint4* __restrict__ vf_q,
                                                 const uint4* __restrict__ pf_q, int i0, int t) {
    int p = t >> 2, q = t & 3;
    uint4 a = vf_q[(size_t)svx[p] * 4 + q];      // pvf -> cols 0..31
    *(uint4*)&cat[p][q * 8] = a;
    uint4 b = pf_q[((size_t)i0 + p) * 4 + q];    // pf -> cols 32..63
    *(uint4*)&cat[p][32 + q * 8] = b;
}

// fuse layer: f[tn][e] = relu(cat @ fu_w + fu_b), tile tn over 64 outputs, e over 4 rows
static __device__ __forceinline__ void gemm_fuse(const unsigned short (*cat)[72],
                                                 const unsigned short* __restrict__ WTfu,
                                                 const float* __restrict__ bias,
                                                 int w, int lane, float f[4][4]) {
    int m = lane & 15, quad = lane >> 4;
    bf16x8_t a0 = *(const bf16x8_t*)&cat[w * 16 + m][quad * 8];
    bf16x8_t a1 = *(const bf16x8_t*)&cat[w * 16 + m][32 + quad * 8];
#pragma unroll
    for (int tn = 0; tn < 4; ++tn) {
        bf16x8_t b0 = *(const bf16x8_t*)(WTfu + (tn * 16 + m) * 64 + quad * 8);
        bf16x8_t b1 = *(const bf16x8_t*)(WTfu + (tn * 16 + m) * 64 + 32 + quad * 8);
        f32x4_t acc = {0.f, 0.f, 0.f, 0.f};
        acc = MFMA16(a0, b0, acc);
        acc = MFMA16(a1, b1, acc);
        float bs = bias[tn * 16 + m];
#pragma unroll
        for (int e = 0; e < 4; ++e) f[tn][e] = fmaxf(acc[e] + bs, 0.f);
    }
}

// ---------- K3: fuse GEMM + per-batch sums ----------
__global__ __launch_bounds__(256) void k3_mfma(const int* __restrict__ bid, const int* __restrict__ pv,
                                               const uint4* __restrict__ pf_q,
                                               const uint4* __restrict__ vf_q,
                                               const float* __restrict__ W,
                                               const unsigned short* __restrict__ WTfu,
                                               float* __restrict__ bsum) {
    __shared__ __align__(16) unsigned short cat[64][72];
    __shared__ __align__(16) unsigned short ft[64][72];
    __shared__ int svx[64], sbid[64];
    __shared__ float red[4][64];
    __shared__ int sflag;
    int t = threadIdx.x;
    int i0 = blockIdx.x * 64;
    if (t == 0) sflag = 1;
    if (t < 64) { svx[t] = pv[i0 + t]; sbid[t] = bid[i0 + t]; }
    __syncthreads();
    if (t < 64 && sbid[t] != sbid[0]) sflag = 0;
    stage_cat(cat, svx, vf_q, pf_q, i0, t);
    __syncthreads();

    int lane = t & 63, w = t >> 6;
    int m = lane & 15, quad = lane >> 4;
    float f[4][4];
    gemm_fuse(cat, WTfu, W + O_FUB, w, lane, f);
#pragma unroll
    for (int tn = 0; tn < 4; ++tn)
#pragma unroll
        for (int e = 0; e < 4; ++e)
            ft[w * 16 + quad * 4 + e][tn * 16 + m] = f2us(f[tn][e]);
    __syncthreads();

    int c = t & 63, g = t >> 6;
    if (sflag) {   // uniform batch in block (all but ~3 blocks)
        float s = 0.f;
#pragma unroll
        for (int p = 0; p < 16; ++p) s += us2f(ft[g * 16 + p][c]);
        red[g][c] = s;
        __syncthreads();
        if (t < 64) atomicAdd(&bsum[sbid[0] * 64 + t], red[0][t] + red[1][t] + red[2][t] + red[3][t]);
    } else {       // boundary block: per-point atomics (rare)
#pragma unroll
        for (int p = 0; p < 16; ++p)
            atomicAdd(&bsum[sbid[g * 16 + p] * 64 + c], us2f(ft[g * 16 + p][c]));
    }
}

// ---------- K4: SE gate ----------
__global__ void k4_gate(const float* __restrict__ bsum, const float* __restrict__ bcnt,
                        const float* __restrict__ W, float* __restrict__ gate) {
    __shared__ float m[4][64];
    __shared__ float hid[4][4];
    int tid = threadIdx.x, b = tid >> 6, c = tid & 63;
    m[b][c] = bsum[tid] / fmaxf(bcnt[b], 1.f);
    __syncthreads();
    if (c < 4) {
        const float* w = W + O_SE1W;
        float a = (W + O_SE1B)[c];
        for (int k = 0; k < 64; ++k) a = fmaf(m[b][k], w[k * 4 + c], a);
        hid[b][c] = fmaxf(a, 0.f);
    }
    __syncthreads();
    const float* w2 = W + O_SE2W;
    float g = (W + O_SE2B)[c];
#pragma unroll
    for (int h = 0; h < 4; ++h) g = fmaf(hid[b][h], w2[h * 64 + c], g);
    gate[tid] = 1.f + 1.f / (1.f + expf(-g));   // (1 + sigmoid)
}

// ---------- K5: fuse GEMM + gate + cls GEMMs + store ----------
__global__ __launch_bounds__(256) void k5_mfma(const int* __restrict__ bid, const int* __restrict__ pv,
                                               const uint4* __restrict__ pf_q,
                                               const uint4* __restrict__ vf_q,
                                               const float* __restrict__ W,
                                               const unsigned short* __restrict__ WTfu,
                                               const unsigned short* __restrict__ WTc1,
                                               const unsigned short* __restrict__ WTc2,
                                               const float* __restrict__ gate,
                                               const int* __restrict__ flags,
                                               void* __restrict__ out) {
    __shared__ __align__(16) unsigned short cat[64][72];
    __shared__ __align__(16) unsigned short ft[64][72];
    __shared__ __align__(16) unsigned short ht[64][40];
    __shared__ float ot[64][21];
    __shared__ float sgate[256];
    __shared__ int svx[64], sbid[64];
    int t = threadIdx.x;
    int i0 = blockIdx.x * 64;
    sgate[t] = gate[t];
    if (t < 64) { svx[t] = pv[i0 + t]; sbid[t] = bid[i0 + t]; }
    __syncthreads();
    stage_cat(cat, svx, vf_q, pf_q, i0, t);
    __syncthreads();

    int lane = t & 63, w = t >> 6;
    int m = lane & 15, quad = lane >> 4;
    float f[4][4];
    gemm_fuse(cat, WTfu, W + O_FUB, w, lane, f);
#pragma unroll
    for (int tn = 0; tn < 4; ++tn) {
        int c = tn * 16 + m;
#pragma unroll
        for (int e = 0; e < 4; ++e) {
            int r = w * 16 + quad * 4 + e;
            ft[r][c] = f2us(f[tn][e] * sgate[sbid[r] * 64 + c]);
        }
    }
    __syncthreads();

    // cls1: 64 -> 32, relu
    bf16x8_t a0 = *(const bf16x8_t*)&ft[w * 16 + m][quad * 8];
    bf16x8_t a1 = *(const bf16x8_t*)&ft[w * 16 + m][32 + quad * 8];
#pragma unroll
    for (int tn = 0; tn < 2; ++tn) {
        bf16x8_t b0 = *(const bf16x8_t*)(WTc1 + (tn * 16 + m) * 64 + quad * 8);
        bf16x8_t b1 = *(const bf16x8_t*)(WTc1 + (tn * 16 + m) * 64 + 32 + quad * 8);
        f32x4_t acc = {0.f, 0.f, 0.f, 0.f};
        acc = MFMA16(a0, b0, acc);
        acc = MFMA16(a1, b1, acc);
        float bs = W[O_CLS1B + tn * 16 + m];
#pragma unroll
        for (int e = 0; e < 4; ++e)
            ht[w * 16 + quad * 4 + e][tn * 16 + m] = f2us(fmaxf(acc[e] + bs, 0.f));
    }
    __syncthreads();

    // cls2: 32 -> 20, no bias
    bf16x8_t a2 = *(const bf16x8_t*)&ht[w * 16 + m][quad * 8];
#pragma unroll
    for (int tn = 0; tn < 2; ++tn) {
        bf16x8_t b = *(const bf16x8_t*)(WTc2 + (tn * 16 + m) * 32 + quad * 8);
        f32x4_t acc = {0.f, 0.f, 0.f, 0.f};
        acc = MFMA16(a2, b, acc);
        int c = tn * 16 + m;
        if (c < NCLS) {
#pragma unroll
            for (int e = 0; e < 4; ++e) ot[w * 16 + quad * 4 + e][c] = acc[e];
        }
    }
    __syncthreads();

    int of32 = flags[0];
    if (of32) {
        float* of = (float*)out + (size_t)i0 * NCLS;
        for (int idx = t; idx < 64 * NCLS; idx += 256) {
            int p = idx / NCLS, c = idx - p * NCLS;
            of[idx] = ot[p][c];
        }
    } else {
        unsigned short* ob = (unsigned short*)out + (size_t)i0 * NCLS;
        for (int idx = t; idx < 64 * NCLS; idx += 256) {
            int p = idx / NCLS, c = idx - p * NCLS;
            ob[idx] = f2us(ot[p][c]);
        }
    }
}

extern "C" void kernel_launch(void* const* d_in, const int* in_sizes, int n_in,
                              void* d_out, int out_size, void* d_ws, size_t ws_size,
                              hipStream_t stream) {
    WPtrs p;
    p.pe_w1 = d_in[2];  p.pe_g1 = d_in[3];  p.pe_b1 = d_in[4];
    p.pe_w2 = d_in[5];  p.pe_g2 = d_in[6];  p.pe_b2 = d_in[7];
    p.pe_w3 = d_in[8];  p.pe_g3 = d_in[9];  p.pe_b3 = d_in[10];
    p.ve_w1 = d_in[11]; p.ve_g1 = d_in[12]; p.ve_b1 = d_in[13];
    p.ve_w2 = d_in[14]; p.ve_g2 = d_in[15]; p.ve_b2 = d_in[16];
    p.fu_w  = d_in[17]; p.fu_g  = d_in[18]; p.fu_b  = d_in[19];
    p.se_w1 = d_in[20]; p.se_b1 = d_in[21];
    p.se_w2 = d_in[22]; p.se_b2 = d_in[23];
    p.cls_w1 = d_in[24]; p.cls_g1 = d_in[25]; p.cls_b1 = d_in[26];
    p.cls_w2 = d_in[27];
    p.aux_w1 = d_in[28]; p.aux_g1 = d_in[29]; p.aux_b1 = d_in[30];
    p.aux_w2 = d_in[31];

    float* base = (float*)d_ws;
    float4* ptsC = (float4*)(base + L_PTSC);
    int*   pvN  = (int*)(base + L_PV);
    int*   bidN = (int*)(base + L_BID);
    int*   cnt  = (int*)(base + L_CNT);
    float* bsum = base + L_BSUM;
    float* bcnt = base + L_BCNT;
    float* gate = base + L_GATE;
    int*   flags = (int*)(base + L_FLAG);
    int*   offs = (int*)(base + L_OFFS);
    int*   offw = (int*)(base + L_OFFW);
    int*   bs1  = (int*)(base + L_BS1);
    int*   bb   = (int*)(base + L_BB);
    int*   idxs = (int*)(base + L_IDX);
    float* W    = base + L_W;
    unsigned short* WT = (unsigned short*)(base + L_WT);
    unsigned short* wtfu = WT;
    unsigned short* wtc1 = WT + 4096;
    unsigned short* wtc2 = WT + 4096 + 2048;
    unsigned* vf_u = (unsigned*)(base + L_VFU);
    uint4* pf_q = (uint4*)(base + L_PFQ);

    constexpr int NBP = (NPTS + 255) / 256;       // point-grid blocks
    constexpr int NBV = (NVOX + 255) / 256;       // voxel-grid blocks
    constexpr int NBS = (NVOX + 1023) / 1024;     // scan blocks (196)
    constexpr int NBM = NPTS / 64;                // MFMA blocks (64 pts each, exact)

    // zero cnt + bsum + bcnt (contiguous)
    hipMemsetAsync(cnt, 0, (NVOX + 260) * sizeof(float), stream);
    k0_detect<<<1, 64, 0, stream>>>((const unsigned short*)d_in[0], (const unsigned*)d_in[1], flags);
    k0_norm<<<NBP, 256, 0, stream>>>(d_in[0], d_in[1], flags, ptsC, pvN, bidN, cnt, bcnt);
    k0_prep<<<1, 256, 0, stream>>>(p, flags, W, WT);
    k_scan1<<<NBS, 256, 0, stream>>>(cnt, bs1);
    k_scan2<<<1, 256, 0, stream>>>(bs1, bb, NBS);
    k_scan3<<<NBS, 256, 0, stream>>>(cnt, bb, offs, offw);
    k_scatter<<<NBP, 256, 0, stream>>>(pvN, offw, idxs);
    k1_point<<<NBP, 256, 0, stream>>>(ptsC, W, pf_q);
    k_voxmlp<<<NBV, 256, 0, stream>>>(offs, cnt, idxs, pf_q, W, flags, vf_u, d_out);
    k3_mfma<<<NBM, 256, 0, stream>>>(bidN, pvN, pf_q, (const uint4*)vf_u, W, wtfu, bsum);
    k4_gate<<<1, 256, 0, stream>>>(bsum, bcnt, W, gate);
    k5_mfma<<<NBM, 256, 0, stream>>>(bidN, pvN, pf_q, (const uint4*)vf_u, W, wtfu, wtc1, wtc2, gate, flags, d_out);
}

// Round 5
// 702.191 us; speedup vs baseline: 3.3506x; 1.3373x over previous
//
#include <hip/hip_runtime.h>
#include <hip/hip_bf16.h>

#define NPTS 1000000
#define NVOX 200000
#define NCLS 20

typedef __hip_bfloat16 bf16;
typedef __attribute__((ext_vector_type(8))) short bf16x8_t;
typedef __attribute__((ext_vector_type(4))) float f32x4_t;
#define MFMA16(a, b, c) __builtin_amdgcn_mfma_f32_16x16x32_bf16(a, b, c, 0, 0, 0)

// ---------- workspace layout (fp32 words) ----------
constexpr size_t L_PTSC = 0;                          // N float4 coords
constexpr size_t L_PV   = L_PTSC + (size_t)NPTS * 4;  // N int32 voxel ids
constexpr size_t L_BID  = L_PV + NPTS;                // N int32 batch ids
constexpr size_t L_CNT  = L_BID + NPTS;               // V counts (zero)
constexpr size_t L_BSUM = L_CNT + NVOX;               // 8 x 256 replicated (zero)
constexpr size_t L_BCNT = L_BSUM + 2048;              // 4 (zero)
constexpr size_t L_GATE = L_BCNT + 4;                 // 256
constexpr size_t L_FLAG = L_GATE + 256;               // 4
constexpr size_t L_OFFS = L_FLAG + 4;                 // V
constexpr size_t L_OFFW = L_OFFS + NVOX;              // V (scatter cursor)
constexpr size_t L_BS1  = L_OFFW + NVOX;              // 256 block sums
constexpr size_t L_BB   = L_BS1 + 256;                // 256 block bases
constexpr size_t L_IDX  = L_BB + 256;                 // N sorted point ids
constexpr size_t L_W    = L_IDX + NPTS;               // folded weights fp32
// weight offsets inside W
constexpr int O_PE1W = 0;      constexpr int O_PE1B = 128;
constexpr int O_PE2W = 160;    constexpr int O_PE2B = 2208;
constexpr int O_PE3W = 2272;   constexpr int O_PE3B = 4320;
constexpr int O_VE1W = 4352;   constexpr int O_VE1B = 5376;
constexpr int O_VE2W = 5408;   constexpr int O_VE2B = 6432;
constexpr int O_FUW  = 6464;   constexpr int O_FUB  = 10560;
constexpr int O_SE1W = 10624;  constexpr int O_SE1B = 10880;
constexpr int O_SE2W = 10884;  constexpr int O_SE2B = 11140;
constexpr int O_CLS1W = 11204; constexpr int O_CLS1B = 13252;
constexpr int O_CLS2W = 13284;
constexpr int O_AUX1W = 13924; constexpr int O_AUX1B = 14948;
constexpr int O_AUX2W = 14980;
constexpr int W_TOTAL = 15620;
constexpr size_t L_WT  = L_W + W_TOTAL;               // bf16 transposed weights
static_assert((L_WT * 4) % 16 == 0, "WT alignment");
constexpr size_t L_VFU = L_WT + (4096 + 2048 + 1024) / 2;
constexpr size_t L_PFQ = L_VFU + (size_t)NVOX * 16;   // N*16 packed bf16 pairs (row-major, 64B/pt)
static_assert((L_VFU * 4) % 16 == 0, "vf alignment");
static_assert((L_PFQ * 4) % 16 == 0, "pf alignment");

static __device__ __forceinline__ float b2f(bf16 v) { return __bfloat162float(v); }
static __device__ __forceinline__ float us2f(unsigned short u) { return __uint_as_float((unsigned)u << 16); }
static __device__ __forceinline__ unsigned short f2us(float f) {
    unsigned u = __float_as_uint(f);
    u += 0x7fffu + ((u >> 16) & 1u);
    return (unsigned short)(u >> 16);
}
static __device__ __forceinline__ unsigned pack2(float a, float b) {
    return (unsigned)f2us(a) | ((unsigned)f2us(b) << 16);
}
static __device__ __forceinline__ void unpack2(unsigned u, float& a, float& b) {
    a = __uint_as_float(u << 16);
    b = __uint_as_float(u & 0xffff0000u);
}
static __device__ __forceinline__ float rdf(const void* p, size_t idx, int fp32) {
    return fp32 ? ((const float*)p)[idx] : b2f(((const bf16*)p)[idx]);
}

template <int K, int M, bool RELU, bool BIAS>
static __device__ __forceinline__ void dense(const float* __restrict__ x, float* __restrict__ y,
                                             const float* __restrict__ w, const float* __restrict__ b) {
#pragma unroll
    for (int j = 0; j < M; ++j) {
        float a = BIAS ? b[j] : 0.f;
#pragma unroll
        for (int k = 0; k < K; ++k) a = fmaf(x[k], w[k * M + j], a);
        y[j] = RELU ? fmaxf(a, 0.f) : a;
    }
}

static __device__ __forceinline__ int block_excl_scan(int v, int t) {
    __shared__ int sh[2][256];
    int cur = 0;
    sh[0][t] = v; __syncthreads();
#pragma unroll
    for (int off = 1; off < 256; off <<= 1) {
        int val = sh[cur][t];
        if (t >= off) val += sh[cur][t - off];
        sh[cur ^ 1][t] = val; __syncthreads();
        cur ^= 1;
    }
    return sh[cur][t] - v;
}

// ---------- K0a: detect input dtypes from data ----------
__global__ void k0_detect(const unsigned short* __restrict__ ptsu,
                          const unsigned* __restrict__ pvu, int* __restrict__ flags) {
    if (threadIdx.x == 0) {
        int fp32 = (ptsu[1] == 0 && ptsu[11] == 0) ? 1 : 0;
        int i64 = (pvu[1] == 0 && pvu[3] == 0 && pvu[5] == 0 && pvu[7] == 0) ? 1 : 0;
        flags[0] = fp32;
        flags[1] = i64;
    }
}

// ---------- K0b: normalize points/ids + voxel histogram + batch counts ----------
__global__ __launch_bounds__(256) void k0_norm(const void* __restrict__ pts_raw,
                                               const void* __restrict__ pv_raw,
                                               const int* __restrict__ flags,
                                               float4* __restrict__ ptsC,
                                               int* __restrict__ pvN,
                                               int* __restrict__ bidN,
                                               int* __restrict__ cnt,
                                               float* __restrict__ bcnt) {
    int i = blockIdx.x * 256 + threadIdx.x;
    bool valid = i < NPTS;
    int fp32 = flags[0], i64 = flags[1];
    int b = 0;
    if (valid) {
        float4 c;
        c.x = rdf(pts_raw, (size_t)i * 5 + 1, fp32);
        c.y = rdf(pts_raw, (size_t)i * 5 + 2, fp32);
        c.z = rdf(pts_raw, (size_t)i * 5 + 3, fp32);
        c.w = rdf(pts_raw, (size_t)i * 5 + 4, fp32);
        ptsC[i] = c;
        b = (int)rdf(pts_raw, (size_t)i * 5, fp32);
        bidN[i] = b;
        int v = i64 ? (int)((const long long*)pv_raw)[i] : ((const int*)pv_raw)[i];
        pvN[i] = v;
        atomicAdd(&cnt[v], 1);
    }
    __shared__ int sb0, sflag;
    if (threadIdx.x == 0) { sb0 = b; sflag = 1; }
    __syncthreads();
    if (valid && b != sb0) sflag = 0;
    __syncthreads();
    if (sflag) {
        if (threadIdx.x == 0) {
            int vc = NPTS - blockIdx.x * 256; if (vc > 256) vc = 256;
            atomicAdd(&bcnt[sb0], (float)vc);
        }
    } else if (valid) {
        atomicAdd(&bcnt[b], 1.f);
    }
}

// ---------- K0c: fold BN into weights + build bf16 transposed weights ----------
struct WPtrs {
    const void *pe_w1, *pe_g1, *pe_b1, *pe_w2, *pe_g2, *pe_b2, *pe_w3, *pe_g3, *pe_b3;
    const void *ve_w1, *ve_g1, *ve_b1, *ve_w2, *ve_g2, *ve_b2;
    const void *fu_w, *fu_g, *fu_b;
    const void *se_w1, *se_b1, *se_w2, *se_b2;
    const void *cls_w1, *cls_g1, *cls_b1, *cls_w2;
    const void *aux_w1, *aux_g1, *aux_b1, *aux_w2;
};

static __device__ void foldw(float* d, const void* w, const void* g, int K, int M, int fp32) {
    const float INV = 0.9999950000374997f;  // 1/sqrt(1+1e-5)
    for (int idx = threadIdx.x; idx < K * M; idx += 256)
        d[idx] = rdf(w, idx, fp32) * (rdf(g, idx % M, fp32) * INV);
}
static __device__ void cpv(float* d, const void* s, int n, int fp32) {
    for (int idx = threadIdx.x; idx < n; idx += 256) d[idx] = rdf(s, idx, fp32);
}

__global__ void k0_prep(WPtrs p, const int* __restrict__ flags, float* __restrict__ W,
                        unsigned short* __restrict__ WT) {
    int f = flags[0];
    foldw(W + O_PE1W, p.pe_w1, p.pe_g1, 4, 32, f);   cpv(W + O_PE1B, p.pe_b1, 32, f);
    foldw(W + O_PE2W, p.pe_w2, p.pe_g2, 32, 64, f);  cpv(W + O_PE2B, p.pe_b2, 64, f);
    foldw(W + O_PE3W, p.pe_w3, p.pe_g3, 64, 32, f);  cpv(W + O_PE3B, p.pe_b3, 32, f);
    foldw(W + O_VE1W, p.ve_w1, p.ve_g1, 32, 32, f);  cpv(W + O_VE1B, p.ve_b1, 32, f);
    foldw(W + O_VE2W, p.ve_w2, p.ve_g2, 32, 32, f);  cpv(W + O_VE2B, p.ve_b2, 32, f);
    foldw(W + O_FUW,  p.fu_w,  p.fu_g,  64, 64, f);  cpv(W + O_FUB,  p.fu_b, 64, f);
    cpv(W + O_SE1W, p.se_w1, 256, f);  cpv(W + O_SE1B, p.se_b1, 4, f);
    cpv(W + O_SE2W, p.se_w2, 256, f);  cpv(W + O_SE2B, p.se_b2, 64, f);
    foldw(W + O_CLS1W, p.cls_w1, p.cls_g1, 64, 32, f); cpv(W + O_CLS1B, p.cls_b1, 32, f);
    cpv(W + O_CLS2W, p.cls_w2, 640, f);
    foldw(W + O_AUX1W, p.aux_w1, p.aux_g1, 32, 32, f); cpv(W + O_AUX1B, p.aux_b1, 32, f);
    cpv(W + O_AUX2W, p.aux_w2, 640, f);
    __syncthreads();
    unsigned short* wtfu = WT;                 // [64][64]
    unsigned short* wtc1 = WT + 4096;          // [32][64]
    unsigned short* wtc2 = WT + 4096 + 2048;   // [32][32], rows >= 20 zero
    for (int idx = threadIdx.x; idx < 4096; idx += 256) {
        int n = idx >> 6, k = idx & 63;
        wtfu[idx] = f2us(W[O_FUW + k * 64 + n]);
    }
    for (int idx = threadIdx.x; idx < 2048; idx += 256) {
        int n = idx >> 6, k = idx & 63;
        wtc1[idx] = f2us(W[O_CLS1W + k * 32 + n]);
    }
    for (int idx = threadIdx.x; idx < 1024; idx += 256) {
        int n = idx >> 5, k = idx & 31;
        wtc2[idx] = (n < NCLS) ? f2us(W[O_CLS2W + k * NCLS + n]) : (unsigned short)0;
    }
}

// ---------- counting-sort scan ----------
__global__ __launch_bounds__(256) void k_scan1(const int* __restrict__ cnt, int* __restrict__ bs) {
    int t = threadIdx.x;
    int base = blockIdx.x * 1024 + t * 4;
    int s = 0;
#pragma unroll
    for (int k = 0; k < 4; ++k) { int idx = base + k; if (idx < NVOX) s += cnt[idx]; }
    __shared__ int red[256];
    red[t] = s; __syncthreads();
    for (int off = 128; off > 0; off >>= 1) { if (t < off) red[t] += red[t + off]; __syncthreads(); }
    if (t == 0) bs[blockIdx.x] = red[0];
}

__global__ __launch_bounds__(256) void k_scan2(const int* __restrict__ bs, int* __restrict__ bb, int nb) {
    int t = threadIdx.x;
    int v = (t < nb) ? bs[t] : 0;
    int e = block_excl_scan(v, t);
    bb[t] = e;
}

__global__ __launch_bounds__(256) void k_scan3(const int* __restrict__ cnt, const int* __restrict__ bb,
                                               int* __restrict__ offs, int* __restrict__ offw) {
    int t = threadIdx.x;
    int base = blockIdx.x * 1024 + t * 4;
    int c[4]; int s = 0;
#pragma unroll
    for (int k = 0; k < 4; ++k) { int idx = base + k; c[k] = (idx < NVOX) ? cnt[idx] : 0; s += c[k]; }
    int run = bb[blockIdx.x] + block_excl_scan(s, t);
#pragma unroll
    for (int k = 0; k < 4; ++k) {
        int idx = base + k;
        if (idx < NVOX) { offs[idx] = run; offw[idx] = run; run += c[k]; }
    }
}

__global__ __launch_bounds__(256) void k_scatter(const int* __restrict__ pvN,
                                                 int* __restrict__ offw, int* __restrict__ idx_sorted) {
    int i = blockIdx.x * 256 + threadIdx.x;
    if (i >= NPTS) return;
    int pos = atomicAdd(&offw[pvN[i]], 1);
    idx_sorted[pos] = i;
}

// ---------- K1: point MLP (4->32->64->32) ----------
__global__ __launch_bounds__(256) void k1_point(const float4* __restrict__ ptsC,
                                                const float* __restrict__ W,
                                                uint4* __restrict__ pf_q) {
    int i = blockIdx.x * 256 + threadIdx.x;
    if (i >= NPTS) return;
    float4 c = ptsC[i];
    float x[4] = {c.x, c.y, c.z, c.w};
    float h1[32], h2[64], pf[32];
    dense<4, 32, true, true>(x, h1, W + O_PE1W, W + O_PE1B);
    dense<32, 64, true, true>(h1, h2, W + O_PE2W, W + O_PE2B);
    dense<64, 32, true, true>(h2, pf, W + O_PE3W, W + O_PE3B);
#pragma unroll
    for (int t = 0; t < 4; ++t)
        pf_q[(size_t)i * 4 + t] = make_uint4(pack2(pf[8*t+0], pf[8*t+1]), pack2(pf[8*t+2], pf[8*t+3]),
                                             pack2(pf[8*t+4], pf[8*t+5]), pack2(pf[8*t+6], pf[8*t+7]));
}

// ---------- K2: per-voxel max gather + voxel MLP + aux head ----------
__global__ __launch_bounds__(256) void k_voxmlp(const int* __restrict__ offs, const int* __restrict__ cnt,
                                                const int* __restrict__ idx_sorted,
                                                const uint4* __restrict__ pf_q,
                                                const float* __restrict__ W,
                                                const int* __restrict__ flags,
                                                unsigned* __restrict__ vf_u,
                                                void* __restrict__ outbase) {
    int v = blockIdx.x * 256 + threadIdx.x;
    if (v >= NVOX) return;
    int of32 = flags[0];
    float mx[32];
#pragma unroll
    for (int c = 0; c < 32; ++c) mx[c] = 0.f;
    int s = offs[v], n = cnt[v];
    for (int p = 0; p < n; ++p) {
        int j = idx_sorted[s + p];
#pragma unroll
        for (int t = 0; t < 4; ++t) {
            uint4 q = pf_q[(size_t)j * 4 + t];
            float a, b;
            unpack2(q.x, a, b); mx[8*t+0] = fmaxf(mx[8*t+0], a); mx[8*t+1] = fmaxf(mx[8*t+1], b);
            unpack2(q.y, a, b); mx[8*t+2] = fmaxf(mx[8*t+2], a); mx[8*t+3] = fmaxf(mx[8*t+3], b);
            unpack2(q.z, a, b); mx[8*t+4] = fmaxf(mx[8*t+4], a); mx[8*t+5] = fmaxf(mx[8*t+5], b);
            unpack2(q.w, a, b); mx[8*t+6] = fmaxf(mx[8*t+6], a); mx[8*t+7] = fmaxf(mx[8*t+7], b);
        }
    }
    float v1[32], vf[32], a1[32], o[20];
    dense<32, 32, true, true>(mx, v1, W + O_VE1W, W + O_VE1B);
    dense<32, 32, true, true>(v1, vf, W + O_VE2W, W + O_VE2B);
#pragma unroll
    for (int c = 0; c < 16; ++c) vf_u[(size_t)v * 16 + c] = pack2(vf[2*c], vf[2*c+1]);
    dense<32, 32, true, true>(v1, a1, W + O_AUX1W, W + O_AUX1B);
    dense<32, 20, false, false>(a1, o, W + O_AUX2W, nullptr);
    if (of32) {
        float* auxf = (float*)outbase + (size_t)NPTS * NCLS + (size_t)v * NCLS;
#pragma unroll
        for (int t = 0; t < NCLS; ++t) auxf[t] = o[t];
    } else {
        unsigned* auxu = (unsigned*)((bf16*)outbase + (size_t)NPTS * NCLS);
#pragma unroll
        for (int t = 0; t < 10; ++t) auxu[(size_t)v * 10 + t] = pack2(o[2*t], o[2*t+1]);
    }
}

// ---------- K3: fuse GEMM (direct-frag gather) + per-batch sums ----------
// 256 pts/block, 64/wave (4 tiles of 16 rows), barrier-free hot loop.
__global__ __launch_bounds__(256) void k3_mfma(const int* __restrict__ bid, const int* __restrict__ pv,
                                               const uint4* __restrict__ pf_q,
                                               const uint4* __restrict__ vf_q,
                                               const float* __restrict__ W,
                                               const unsigned short* __restrict__ WTfu,
                                               float* __restrict__ bsum8) {
    __shared__ int sbid[256];
    __shared__ float red[4][64];
    __shared__ int sflag;
    int t = threadIdx.x;
    int i0 = blockIdx.x * 256;
    int nval = NPTS - i0; if (nval > 256) nval = 256;   // multiple of 64
    if (t < nval) sbid[t] = bid[i0 + t];
    if (t == 0) sflag = (bid[i0] == bid[i0 + nval - 1]) ? 1 : 0;

    int lane = t & 63, w = t >> 6;
    int m = lane & 15, quad = lane >> 4;
    // hoisted B-frags + bias (wave-uniform reuse across 4 tiles)
    bf16x8_t bw0[4], bw1[4];
    float bias[4];
#pragma unroll
    for (int tn = 0; tn < 4; ++tn) {
        bw0[tn] = *(const bf16x8_t*)(WTfu + (tn * 16 + m) * 64 + quad * 8);
        bw1[tn] = *(const bf16x8_t*)(WTfu + (tn * 16 + m) * 64 + 32 + quad * 8);
        bias[tn] = W[O_FUB + tn * 16 + m];
    }
    __syncthreads();
    int uni = sflag;
    int b0 = sbid[0];
    int rep = (blockIdx.x & 7) * 256;
    int ntiles = (nval - w * 64 >= 64) ? 4 : 0;

    float csum[4] = {0.f, 0.f, 0.f, 0.f};
#pragma unroll
    for (int tt = 0; tt < 4; ++tt) {
        if (tt >= ntiles) break;
        int rbase = i0 + w * 64 + tt * 16;
        int arow = rbase + m;
        int pvr = pv[arow];
        uint4 va = vf_q[(size_t)pvr * 4 + quad];
        uint4 vb = pf_q[(size_t)arow * 4 + quad];
        bf16x8_t a0 = *(bf16x8_t*)&va;
        bf16x8_t a1 = *(bf16x8_t*)&vb;
        float f[4][4];
#pragma unroll
        for (int tn = 0; tn < 4; ++tn) {
            f32x4_t acc = {0.f, 0.f, 0.f, 0.f};
            acc = MFMA16(a0, bw0[tn], acc);
            acc = MFMA16(a1, bw1[tn], acc);
#pragma unroll
            for (int e = 0; e < 4; ++e) f[tn][e] = fmaxf(acc[e] + bias[tn], 0.f);
        }
        if (uni) {
#pragma unroll
            for (int tn = 0; tn < 4; ++tn) {
                float s = f[tn][0] + f[tn][1] + f[tn][2] + f[tn][3];
                s += __shfl_xor(s, 16);
                s += __shfl_xor(s, 32);
                csum[tn] += s;
            }
        } else {   // batch-boundary block (~3 total): per-row atomics
#pragma unroll
            for (int tn = 0; tn < 4; ++tn)
#pragma unroll
                for (int e = 0; e < 4; ++e)
                    atomicAdd(&bsum8[rep + sbid[rbase - i0 + quad * 4 + e] * 64 + tn * 16 + m], f[tn][e]);
        }
    }
    if (uni) {
        float mine = quad == 0 ? csum[0] : quad == 1 ? csum[1] : quad == 2 ? csum[2] : csum[3];
        red[w][quad * 16 + m] = mine;
        __syncthreads();
        if (t < 64) {
            float s = red[0][t] + red[1][t] + red[2][t] + red[3][t];
            atomicAdd(&bsum8[rep + b0 * 64 + t], s);
        }
    }
}

// ---------- K4: SE gate ----------
__global__ void k4_gate(const float* __restrict__ bsum8, const float* __restrict__ bcnt,
                        const float* __restrict__ W, float* __restrict__ gate) {
    __shared__ float m[4][64];
    __shared__ float hid[4][4];
    int tid = threadIdx.x, b = tid >> 6, c = tid & 63;
    float s = 0.f;
#pragma unroll
    for (int r = 0; r < 8; ++r) s += bsum8[r * 256 + tid];
    m[b][c] = s / fmaxf(bcnt[b], 1.f);
    __syncthreads();
    if (c < 4) {
        const float* w = W + O_SE1W;
        float a = (W + O_SE1B)[c];
        for (int k = 0; k < 64; ++k) a = fmaf(m[b][k], w[k * 4 + c], a);
        hid[b][c] = fmaxf(a, 0.f);
    }
    __syncthreads();
    const float* w2 = W + O_SE2W;
    float g = (W + O_SE2B)[c];
#pragma unroll
    for (int h = 0; h < 4; ++h) g = fmaf(hid[b][h], w2[h * 64 + c], g);
    gate[tid] = 1.f + 1.f / (1.f + expf(-g));   // (1 + sigmoid)
}

// ---------- K5: fuse GEMM (direct-frag gather) + gate + cls GEMMs + store ----------
// 256 pts/block, per-wave LDS regions, no __syncthreads in the tile loop.
__global__ __launch_bounds__(256) void k5_mfma(const int* __restrict__ bid, const int* __restrict__ pv,
                                               const uint4* __restrict__ pf_q,
                                               const uint4* __restrict__ vf_q,
                                               const float* __restrict__ W,
                                               const unsigned short* __restrict__ WTfu,
                                               const unsigned short* __restrict__ WTc1,
                                               const unsigned short* __restrict__ WTc2,
                                               const float* __restrict__ gate,
                                               const int* __restrict__ flags,
                                               void* __restrict__ out) {
    __shared__ float sg[256];
    __shared__ int sbid[256];
    __shared__ int sflag;
    __shared__ __align__(16) unsigned short ft[4][16][72];
    __shared__ __align__(16) unsigned short ht[4][16][40];
    __shared__ float ot[4][16][20];
    int t = threadIdx.x;
    int i0 = blockIdx.x * 256;
    int nval = NPTS - i0; if (nval > 256) nval = 256;
    sg[t] = gate[t];
    if (t < nval) sbid[t] = bid[i0 + t];
    if (t == 0) sflag = (bid[i0] == bid[i0 + nval - 1]) ? 1 : 0;

    int lane = t & 63, w = t >> 6;
    int m = lane & 15, quad = lane >> 4;
    // hoisted B-frags + biases
    bf16x8_t bfu0[4], bfu1[4], bc10[2], bc11[2], bc2[2];
    float biasfu[4], biasc1[2];
#pragma unroll
    for (int tn = 0; tn < 4; ++tn) {
        bfu0[tn] = *(const bf16x8_t*)(WTfu + (tn * 16 + m) * 64 + quad * 8);
        bfu1[tn] = *(const bf16x8_t*)(WTfu + (tn * 16 + m) * 64 + 32 + quad * 8);
        biasfu[tn] = W[O_FUB + tn * 16 + m];
    }
#pragma unroll
    for (int tn = 0; tn < 2; ++tn) {
        bc10[tn] = *(const bf16x8_t*)(WTc1 + (tn * 16 + m) * 64 + quad * 8);
        bc11[tn] = *(const bf16x8_t*)(WTc1 + (tn * 16 + m) * 64 + 32 + quad * 8);
        bc2[tn]  = *(const bf16x8_t*)(WTc2 + (tn * 16 + m) * 32 + quad * 8);
        biasc1[tn] = W[O_CLS1B + tn * 16 + m];
    }
    __syncthreads();
    int uni = sflag;
    int of32 = flags[0];
    int ntiles = (nval - w * 64 >= 64) ? 4 : 0;

#pragma unroll 1
    for (int tt = 0; tt < ntiles; ++tt) {
        int rbase = i0 + w * 64 + tt * 16;
        int arow = rbase + m;
        int pvr = pv[arow];
        uint4 va = vf_q[(size_t)pvr * 4 + quad];
        uint4 vb = pf_q[(size_t)arow * 4 + quad];
        bf16x8_t a0 = *(bf16x8_t*)&va;
        bf16x8_t a1 = *(bf16x8_t*)&vb;
        float gcol[4];
        if (uni) {
#pragma unroll
            for (int tn = 0; tn < 4; ++tn) gcol[tn] = sg[sbid[0] * 64 + tn * 16 + m];
        }
        // fuse 64->64 + relu + gate -> ft (per-wave region, wave-sync LDS)
#pragma unroll
        for (int tn = 0; tn < 4; ++tn) {
            f32x4_t acc = {0.f, 0.f, 0.f, 0.f};
            acc = MFMA16(a0, bfu0[tn], acc);
            acc = MFMA16(a1, bfu1[tn], acc);
#pragma unroll
            for (int e = 0; e < 4; ++e) {
                float fv = fmaxf(acc[e] + biasfu[tn], 0.f);
                float g = uni ? gcol[tn] : sg[sbid[rbase - i0 + quad * 4 + e] * 64 + tn * 16 + m];
                ft[w][quad * 4 + e][tn * 16 + m] = f2us(fv * g);
            }
        }
        // cls1 64->32 + relu -> ht
        bf16x8_t c0 = *(const bf16x8_t*)&ft[w][m][quad * 8];
        bf16x8_t c1 = *(const bf16x8_t*)&ft[w][m][32 + quad * 8];
#pragma unroll
        for (int tn = 0; tn < 2; ++tn) {
            f32x4_t acc = {0.f, 0.f, 0.f, 0.f};
            acc = MFMA16(c0, bc10[tn], acc);
            acc = MFMA16(c1, bc11[tn], acc);
#pragma unroll
            for (int e = 0; e < 4; ++e)
                ht[w][quad * 4 + e][tn * 16 + m] = f2us(fmaxf(acc[e] + biasc1[tn], 0.f));
        }
        // cls2 32->20
        bf16x8_t d0 = *(const bf16x8_t*)&ht[w][m][quad * 8];
#pragma unroll
        for (int tn = 0; tn < 2; ++tn) {
            f32x4_t acc = {0.f, 0.f, 0.f, 0.f};
            acc = MFMA16(d0, bc2[tn], acc);
            int c = tn * 16 + m;
            if (c < NCLS) {
#pragma unroll
                for (int e = 0; e < 4; ++e) ot[w][quad * 4 + e][c] = acc[e];
            }
        }
        // store 16 rows x 20 cols (wave-sync LDS readback)
        if (of32) {
            float* of = (float*)out + (size_t)rbase * NCLS;
#pragma unroll
            for (int k = 0; k < 5; ++k) {
                int idx = k * 64 + lane;
                of[idx] = ((const float*)ot[w])[idx];
            }
        } else {
            unsigned* ow = (unsigned*)((unsigned short*)out + (size_t)rbase * NCLS);
#pragma unroll
            for (int k = 0; k < 3; ++k) {
                int idx = k * 64 + lane;
                if (idx < 160) {
                    int p = idx / 10, c2 = idx - p * 10;
                    ow[idx] = pack2(ot[w][p][2 * c2], ot[w][p][2 * c2 + 1]);
                }
            }
        }
    }
}

extern "C" void kernel_launch(void* const* d_in, const int* in_sizes, int n_in,
                              void* d_out, int out_size, void* d_ws, size_t ws_size,
                              hipStream_t stream) {
    WPtrs p;
    p.pe_w1 = d_in[2];  p.pe_g1 = d_in[3];  p.pe_b1 = d_in[4];
    p.pe_w2 = d_in[5];  p.pe_g2 = d_in[6];  p.pe_b2 = d_in[7];
    p.pe_w3 = d_in[8];  p.pe_g3 = d_in[9];  p.pe_b3 = d_in[10];
    p.ve_w1 = d_in[11]; p.ve_g1 = d_in[12]; p.ve_b1 = d_in[13];
    p.ve_w2 = d_in[14]; p.ve_g2 = d_in[15]; p.ve_b2 = d_in[16];
    p.fu_w  = d_in[17]; p.fu_g  = d_in[18]; p.fu_b  = d_in[19];
    p.se_w1 = d_in[20]; p.se_b1 = d_in[21];
    p.se_w2 = d_in[22]; p.se_b2 = d_in[23];
    p.cls_w1 = d_in[24]; p.cls_g1 = d_in[25]; p.cls_b1 = d_in[26];
    p.cls_w2 = d_in[27];
    p.aux_w1 = d_in[28]; p.aux_g1 = d_in[29]; p.aux_b1 = d_in[30];
    p.aux_w2 = d_in[31];

    float* base = (float*)d_ws;
    float4* ptsC = (float4*)(base + L_PTSC);
    int*   pvN  = (int*)(base + L_PV);
    int*   bidN = (int*)(base + L_BID);
    int*   cnt  = (int*)(base + L_CNT);
    float* bsum8 = base + L_BSUM;
    float* bcnt = base + L_BCNT;
    float* gate = base + L_GATE;
    int*   flags = (int*)(base + L_FLAG);
    int*   offs = (int*)(base + L_OFFS);
    int*   offw = (int*)(base + L_OFFW);
    int*   bs1  = (int*)(base + L_BS1);
    int*   bb   = (int*)(base + L_BB);
    int*   idxs = (int*)(base + L_IDX);
    float* W    = base + L_W;
    unsigned short* WT = (unsigned short*)(base + L_WT);
    unsigned short* wtfu = WT;
    unsigned short* wtc1 = WT + 4096;
    unsigned short* wtc2 = WT + 4096 + 2048;
    unsigned* vf_u = (unsigned*)(base + L_VFU);
    uint4* pf_q = (uint4*)(base + L_PFQ);

    constexpr int NBP = (NPTS + 255) / 256;
    constexpr int NBV = (NVOX + 255) / 256;
    constexpr int NBS = (NVOX + 1023) / 1024;
    constexpr int NBM = (NPTS + 255) / 256;   // 3907 (last block 64 pts)

    // zero cnt + bsum8 + bcnt (contiguous)
    hipMemsetAsync(cnt, 0, (NVOX + 2048 + 4) * sizeof(float), stream);
    k0_detect<<<1, 64, 0, stream>>>((const unsigned short*)d_in[0], (const unsigned*)d_in[1], flags);
    k0_norm<<<NBP, 256, 0, stream>>>(d_in[0], d_in[1], flags, ptsC, pvN, bidN, cnt, bcnt);
    k0_prep<<<1, 256, 0, stream>>>(p, flags, W, WT);
    k_scan1<<<NBS, 256, 0, stream>>>(cnt, bs1);
    k_scan2<<<1, 256, 0, stream>>>(bs1, bb, NBS);
    k_scan3<<<NBS, 256, 0, stream>>>(cnt, bb, offs, offw);
    k_scatter<<<NBP, 256, 0, stream>>>(pvN, offw, idxs);
    k1_point<<<NBP, 256, 0, stream>>>(ptsC, W, pf_q);
    k_voxmlp<<<NBV, 256, 0, stream>>>(offs, cnt, idxs, pf_q, W, flags, vf_u, d_out);
    k3_mfma<<<NBM, 256, 0, stream>>>(bidN, pvN, pf_q, (const uint4*)vf_u, W, wtfu, bsum8);
    k4_gate<<<1, 256, 0, stream>>>(bsum8, bcnt, W, gate);
    k5_mfma<<<NBM, 256, 0, stream>>>(bidN, pvN, pf_q, (const uint4*)vf_u, W, wtfu, wtc1, wtc2, gate, flags, d_out);
}